// Round 1
// baseline (40976.935 us; speedup 1.0000x reference)
//
#include <hip/hip_runtime.h>
#include <hip/hip_bf16.h>
#include <math.h>

// ---------------- problem constants ----------------
#define HID    2048
#define NH     16
#define D_NOPE 128
#define D_ROPE 64
#define HD     192      // HEAD_DIM
#define V_DIM  128
#define KV_RANK 512
#define Q_RANK  1536
#define BATCH  2
#define SEQ    2048
#define ROWS   (BATCH*SEQ)   // 4096

// ---------------- RoPE cos/sin table ----------------
// table[pos*64 + i]      = cos(pos * invf_i)   (i in 0..31)
// table[pos*64 + 32 + i] = sin(pos * invf_i)
__global__ void rope_table_kernel(float* __restrict__ table) {
    int idx = blockIdx.x * 256 + threadIdx.x;   // < 2048*64 = 131072
    int pos = idx >> 6, u = idx & 63;
    int i = u & 31;
    // inv_freq = 10000^(-(2i)/64) = exp(-(i/32)*ln(10000))
    float invf = expf((float)i * (-9.210340371976184f / 32.0f));
    float ang = (float)pos * invf;
    table[idx] = (u < 32) ? cosf(ang) : sinf(ang);
}

// ---------------- generic fp32 GEMM: C(M,N) = A(M,K) @ B(K,N), row-major ----
// BM=128, BN=64, BK=16, 256 threads, 8x4 micro-tile.
__global__ __launch_bounds__(256) void sgemm_kernel(
    const float* __restrict__ A, const float* __restrict__ B, float* __restrict__ C,
    int M, int N, int K)
{
    const int tid = threadIdx.x;
    const int tx = tid & 15;       // col group (4 cols)
    const int ty = tid >> 4;       // row group (8 rows)
    const int n0 = blockIdx.x * 64;
    const int m0 = blockIdx.y * 128;

    __shared__ float As[16][136];  // transposed A tile, padded (136*4B row = 16B-mult)
    __shared__ float Bs[16][64];

    float acc[8][4] = {};

    for (int k0 = 0; k0 < K; k0 += 16) {
        // stage A: 128x16 floats, 2 float4 per thread, transpose into As[k][m]
        #pragma unroll
        for (int t = 0; t < 2; t++) {
            int s = tid + t * 256;          // 0..511 float4 slots
            int row = s >> 2, kc = s & 3;
            float4 v = *(const float4*)(A + (size_t)(m0 + row) * K + k0 + kc * 4);
            As[kc*4+0][row] = v.x;
            As[kc*4+1][row] = v.y;
            As[kc*4+2][row] = v.z;
            As[kc*4+3][row] = v.w;
        }
        // stage B: 16x64 floats, 1 float4 per thread
        {
            int krow = tid >> 4, nc = tid & 15;
            float4 v = *(const float4*)(B + (size_t)(k0 + krow) * N + n0 + nc * 4);
            *((float4*)&Bs[krow][nc*4]) = v;
        }
        __syncthreads();

        #pragma unroll
        for (int kk = 0; kk < 16; kk++) {
            float4 a0 = *(const float4*)&As[kk][ty*8];
            float4 a1 = *(const float4*)&As[kk][ty*8+4];
            float4 b  = *(const float4*)&Bs[kk][tx*4];
            float av[8] = {a0.x,a0.y,a0.z,a0.w,a1.x,a1.y,a1.z,a1.w};
            #pragma unroll
            for (int i = 0; i < 8; i++) {
                acc[i][0] += av[i]*b.x; acc[i][1] += av[i]*b.y;
                acc[i][2] += av[i]*b.z; acc[i][3] += av[i]*b.w;
            }
        }
        __syncthreads();
    }

    #pragma unroll
    for (int i = 0; i < 8; i++) {
        float4 v = make_float4(acc[i][0], acc[i][1], acc[i][2], acc[i][3]);
        *((float4*)(C + (size_t)(m0 + ty*8 + i) * N + n0 + tx*4)) = v;
    }
}

// ---------------- RMSNorm(kv_c) + RoPE(k_rope) ----------------
__global__ __launch_bounds__(256) void kv_norm_rope_kernel(
    const float* __restrict__ kv_full,   // (4096, 576)
    const float* __restrict__ w,         // (512,)
    const float* __restrict__ table,
    float* __restrict__ kv_c_norm,       // (4096, 512)
    float* __restrict__ k_rope_out)      // (4096, 64)
{
    const int row = blockIdx.x;
    const int tid = threadIdx.x;
    const float* src = kv_full + (size_t)row * 576;
    float v0 = src[tid], v1 = src[tid + 256];
    float ss = v0*v0 + v1*v1;
    #pragma unroll
    for (int off = 32; off > 0; off >>= 1) ss += __shfl_down(ss, off);
    __shared__ float red[4];
    __shared__ float msh;
    if ((tid & 63) == 0) red[tid >> 6] = ss;
    __syncthreads();
    if (tid == 0) msh = (red[0] + red[1] + red[2] + red[3]) * (1.0f / 512.0f);
    __syncthreads();
    float f = rsqrtf(msh + 1e-6f);
    kv_c_norm[(size_t)row * 512 + tid]       = v0 * f * w[tid];
    kv_c_norm[(size_t)row * 512 + tid + 256] = v1 * f * w[tid + 256];
    if (tid < 32) {
        int pos = row & (SEQ - 1);
        float c = table[pos*64 + tid], s = table[pos*64 + 32 + tid];
        float x1 = src[512 + tid], x2 = src[512 + 32 + tid];
        k_rope_out[(size_t)row * 64 + tid]      = x1*c - x2*s;
        k_rope_out[(size_t)row * 64 + 32 + tid] = x2*c + x1*s;
    }
}

// ---------------- RoPE on q (in place) ----------------
// q: (4096, 16*192). Rotates q[..., h*192+128 .. h*192+191].
__global__ __launch_bounds__(256) void q_rope_kernel(float* __restrict__ q,
                                                     const float* __restrict__ table) {
    int g = blockIdx.x * 8 + (threadIdx.x >> 5);  // (row,h) pair id, < 65536
    int i = threadIdx.x & 31;
    int row = g >> 4, h = g & 15;
    size_t base = (size_t)row * (NH*HD) + h * HD + D_NOPE;
    int pos = row & (SEQ - 1);
    float c = table[pos*64 + i], s = table[pos*64 + 32 + i];
    float x1 = q[base + i], x2 = q[base + 32 + i];
    q[base + i]      = x1*c - x2*s;
    q[base + 32 + i] = x2*c + x1*s;
}

// ---------------- flash attention (causal, online softmax) ----------------
// grid (S/64, H, B), 256 threads. Thread quad (4 lanes) owns one q-row.
__global__ __launch_bounds__(256) void flash_kernel(
    const float* __restrict__ q,       // (4096, 3072) roped
    const float* __restrict__ kv_exp,  // (4096, 4096)  per head: [k_nope 128 | v 128]
    const float* __restrict__ k_rope,  // (4096, 64) roped
    float* __restrict__ attn_out)      // (4096, 2048)
{
    const int qb  = blockIdx.x;   // 0..31
    const int h   = blockIdx.y;   // 0..15
    const int bb  = blockIdx.z;   // 0..1
    const int tid = threadIdx.x;
    const int r   = tid >> 2;     // q-row within tile (0..63)
    const int tx  = tid & 3;      // quad lane: 48-wide slice of head dim

    const int q0 = qb * 64;
    const int row_base = bb * SEQ;
    const int qrow = q0 + r;                 // position in sequence
    const int qtok = row_base + qrow;

    __shared__ float Ks[32][192];  // 24KB  [k_nope | k_rope]
    __shared__ float Vs[32][128];  // 16KB

    float qreg[48];
    {
        const float* qp = q + (size_t)qtok * (NH*HD) + h * HD + tx * 48;
        #pragma unroll
        for (int j = 0; j < 12; j++) {
            float4 v = *(const float4*)(qp + j * 4);
            qreg[j*4+0]=v.x; qreg[j*4+1]=v.y; qreg[j*4+2]=v.z; qreg[j*4+3]=v.w;
        }
    }

    float4 o4[8];
    #pragma unroll
    for (int j = 0; j < 8; j++) o4[j] = make_float4(0.f,0.f,0.f,0.f);
    float m = -INFINITY, l = 0.f;

    const float scale = 0.07216878364870322f;  // 1/sqrt(192)
    const int nkb = (q0 >> 5) + 2;             // 32-key blocks covering keys <= q0+63

    for (int kb = 0; kb < nkb; kb++) {
        const int k0 = kb * 32;
        __syncthreads();   // previous iteration's LDS reads done
        // stage K_nope + V: kv_exp rows (row_base+k0 .. +31), 64 float4 per row
        {
            const float4* src = (const float4*)(kv_exp + (size_t)(row_base + k0) * 4096 + h * 256);
            #pragma unroll
            for (int t = 0; t < 8; t++) {
                int s = tid + t * 256;      // 0..2047
                int c = s >> 6, f = s & 63;
                float4 v = src[(size_t)c * 1024 + f];
                if (f < 32) *((float4*)&Ks[c][f*4]) = v;
                else        *((float4*)&Vs[c][(f-32)*4]) = v;
            }
            const float4* rsrc = (const float4*)(k_rope + (size_t)(row_base + k0) * 64);
            #pragma unroll
            for (int t = 0; t < 2; t++) {
                int s = tid + t * 256;      // 0..511
                int c = s >> 4, f = s & 15;
                *((float4*)&Ks[c][128 + f*4]) = rsrc[c * 16 + f];
            }
        }
        __syncthreads();

        // partial scores over this lane's 48-wide slice, then quad-reduce
        float p[32];
        #pragma unroll
        for (int c = 0; c < 32; c++) {
            float acc = 0.f;
            const float* kp = &Ks[c][tx * 48];
            #pragma unroll
            for (int j = 0; j < 48; j++) acc += qreg[j] * kp[j];
            p[c] = acc;
        }
        #pragma unroll
        for (int c = 0; c < 32; c++) {
            p[c] += __shfl_xor(p[c], 1);
            p[c] += __shfl_xor(p[c], 2);
        }
        // causal mask + scale + online softmax update
        float mnew = m;
        #pragma unroll
        for (int c = 0; c < 32; c++) {
            float sc = (k0 + c <= qrow) ? p[c] * scale : -INFINITY;
            p[c] = sc;
            mnew = fmaxf(mnew, sc);
        }
        float alpha = __expf(m - mnew);
        float ps = 0.f;
        #pragma unroll
        for (int c = 0; c < 32; c++) {
            float e = __expf(p[c] - mnew);
            p[c] = e;
            ps += e;
        }
        l = l * alpha + ps;
        m = mnew;
        #pragma unroll
        for (int j = 0; j < 8; j++) {
            o4[j].x *= alpha; o4[j].y *= alpha; o4[j].z *= alpha; o4[j].w *= alpha;
        }
        // o += p @ V   (tx-rotated chunk order -> quad lanes hit disjoint banks)
        #pragma unroll
        for (int c = 0; c < 32; c++) {
            float pc = p[c];
            const float4* vrow = (const float4*)&Vs[c][tx * 32];
            #pragma unroll
            for (int jj = 0; jj < 8; jj++) {
                int ch = (jj + 2 * tx) & 7;
                float4 v = vrow[ch];
                o4[ch].x += pc * v.x; o4[ch].y += pc * v.y;
                o4[ch].z += pc * v.z; o4[ch].w += pc * v.w;
            }
        }
    }

    float inv_l = 1.0f / l;
    float* op = attn_out + (size_t)qtok * (NH*V_DIM) + h * V_DIM + tx * 32;
    #pragma unroll
    for (int ch = 0; ch < 8; ch++) {
        float4 v = o4[ch];
        v.x *= inv_l; v.y *= inv_l; v.z *= inv_l; v.w *= inv_l;
        *((float4*)(op + ch * 4)) = v;
    }
}

// ---------------- launch ----------------
extern "C" void kernel_launch(void* const* d_in, const int* in_sizes, int n_in,
                              void* d_out, int out_size, void* d_ws, size_t ws_size,
                              hipStream_t stream)
{
    const float* x         = (const float*)d_in[0];  // (2,2048,2048)
    const float* w_q_down  = (const float*)d_in[1];  // (2048,1536)
    const float* w_q_up    = (const float*)d_in[2];  // (1536,3072)
    const float* w_kv_down = (const float*)d_in[3];  // (2048,576)
    const float* kv_norm_w = (const float*)d_in[4];  // (512,)
    const float* w_kv_up   = (const float*)d_in[5];  // (512,4096)
    const float* w_out     = (const float*)d_in[6];  // (2048,2048)
    float* out = (float*)d_out;                      // (2,2048,2048)
    float* ws  = (float*)d_ws;

    // workspace layout (float offsets)
    float* table   = ws;              //  131072
    float* q_down  = ws + 131072;     // 4096*1536
    float* q       = ws + 6422528;    // 4096*3072
    float* kv_full = ws + 19005440;   // 4096*576
    float* kv_c    = ws + 21364736;   // 4096*512
    float* kv_exp  = ws + 23461888;   // 4096*4096
    float* k_rope  = ws + 40239104;   // 4096*64
    float* attn    = ws + 40501248;   // 4096*2048
    // total = 48889856 floats = ~186.5 MB

    rope_table_kernel<<<512, 256, 0, stream>>>(table);

    // q_down = x @ w_q_down   (4096,2048)@(2048,1536)
    sgemm_kernel<<<dim3(1536/64, ROWS/128), 256, 0, stream>>>(x, w_q_down, q_down, ROWS, 1536, 2048);
    // q = q_down @ w_q_up     (4096,1536)@(1536,3072)
    sgemm_kernel<<<dim3(3072/64, ROWS/128), 256, 0, stream>>>(q_down, w_q_up, q, ROWS, 3072, 1536);
    // kv_full = x @ w_kv_down (4096,2048)@(2048,576)
    sgemm_kernel<<<dim3(576/64, ROWS/128), 256, 0, stream>>>(x, w_kv_down, kv_full, ROWS, 576, 2048);
    // rmsnorm + k rope
    kv_norm_rope_kernel<<<ROWS, 256, 0, stream>>>(kv_full, kv_norm_w, table, kv_c, k_rope);
    // kv_exp = kv_c @ w_kv_up (4096,512)@(512,4096)
    sgemm_kernel<<<dim3(4096/64, ROWS/128), 256, 0, stream>>>(kv_c, w_kv_up, kv_exp, ROWS, 4096, 512);
    // rope q in place
    q_rope_kernel<<<8192, 256, 0, stream>>>(q, table);
    // attention
    flash_kernel<<<dim3(SEQ/64, NH, BATCH), 256, 0, stream>>>(q, kv_exp, k_rope, attn);
    // out = attn @ w_out      (4096,2048)@(2048,2048)
    sgemm_kernel<<<dim3(2048/64, ROWS/128), 256, 0, stream>>>(attn, w_out, out, ROWS, 2048, 2048);
}

// Round 2
// 27666.248 us; speedup vs baseline: 1.4811x; 1.4811x over previous
//
#include <hip/hip_runtime.h>
#include <hip/hip_bf16.h>
#include <math.h>

// ---------------- problem constants ----------------
#define HID    2048
#define NH     16
#define D_NOPE 128
#define D_ROPE 64
#define HD     192      // HEAD_DIM
#define V_DIM  128
#define KV_RANK 512
#define Q_RANK  1536
#define BATCH  2
#define SEQ    2048
#define ROWS   (BATCH*SEQ)   // 4096

// ---------------- RoPE cos/sin table ----------------
// table[pos*64 + i]      = cos(pos * invf_i)   (i in 0..31)
// table[pos*64 + 32 + i] = sin(pos * invf_i)
__global__ void rope_table_kernel(float* __restrict__ table) {
    int idx = blockIdx.x * 256 + threadIdx.x;   // < 2048*64 = 131072
    int pos = idx >> 6, u = idx & 63;
    int i = u & 31;
    float invf = expf((float)i * (-9.210340371976184f / 32.0f));
    float ang = (float)pos * invf;
    table[idx] = (u < 32) ? cosf(ang) : sinf(ang);
}

// ---------------- generic fp32 GEMM: C(M,N) = A(M,K) @ B(K,N), row-major ----
// BM=128, BN=64, BK=16, 256 threads, 8x4 micro-tile.
__global__ __launch_bounds__(256) void sgemm_kernel(
    const float* __restrict__ A, const float* __restrict__ B, float* __restrict__ C,
    int M, int N, int K)
{
    const int tid = threadIdx.x;
    const int tx = tid & 15;       // col group (4 cols)
    const int ty = tid >> 4;       // row group (8 rows)
    const int n0 = blockIdx.x * 64;
    const int m0 = blockIdx.y * 128;

    __shared__ float As[16][136];  // transposed A tile, padded
    __shared__ float Bs[16][64];

    float acc[8][4] = {};

    for (int k0 = 0; k0 < K; k0 += 16) {
        #pragma unroll
        for (int t = 0; t < 2; t++) {
            int s = tid + t * 256;          // 0..511 float4 slots
            int row = s >> 2, kc = s & 3;
            float4 v = *(const float4*)(A + (size_t)(m0 + row) * K + k0 + kc * 4);
            As[kc*4+0][row] = v.x;
            As[kc*4+1][row] = v.y;
            As[kc*4+2][row] = v.z;
            As[kc*4+3][row] = v.w;
        }
        {
            int krow = tid >> 4, nc = tid & 15;
            float4 v = *(const float4*)(B + (size_t)(k0 + krow) * N + n0 + nc * 4);
            *((float4*)&Bs[krow][nc*4]) = v;
        }
        __syncthreads();

        #pragma unroll
        for (int kk = 0; kk < 16; kk++) {
            float4 a0 = *(const float4*)&As[kk][ty*8];
            float4 a1 = *(const float4*)&As[kk][ty*8+4];
            float4 b  = *(const float4*)&Bs[kk][tx*4];
            float av[8] = {a0.x,a0.y,a0.z,a0.w,a1.x,a1.y,a1.z,a1.w};
            #pragma unroll
            for (int i = 0; i < 8; i++) {
                acc[i][0] += av[i]*b.x; acc[i][1] += av[i]*b.y;
                acc[i][2] += av[i]*b.z; acc[i][3] += av[i]*b.w;
            }
        }
        __syncthreads();
    }

    #pragma unroll
    for (int i = 0; i < 8; i++) {
        float4 v = make_float4(acc[i][0], acc[i][1], acc[i][2], acc[i][3]);
        *((float4*)(C + (size_t)(m0 + ty*8 + i) * N + n0 + tx*4)) = v;
    }
}

// ---------------- RMSNorm(kv_c) + RoPE(k_rope) ----------------
__global__ __launch_bounds__(256) void kv_norm_rope_kernel(
    const float* __restrict__ kv_full,   // (4096, 576)
    const float* __restrict__ w,         // (512,)
    const float* __restrict__ table,
    float* __restrict__ kv_c_norm,       // (4096, 512)
    float* __restrict__ k_rope_out)      // (4096, 64)
{
    const int row = blockIdx.x;
    const int tid = threadIdx.x;
    const float* src = kv_full + (size_t)row * 576;
    float v0 = src[tid], v1 = src[tid + 256];
    float ss = v0*v0 + v1*v1;
    #pragma unroll
    for (int off = 32; off > 0; off >>= 1) ss += __shfl_down(ss, off);
    __shared__ float red[4];
    __shared__ float msh;
    if ((tid & 63) == 0) red[tid >> 6] = ss;
    __syncthreads();
    if (tid == 0) msh = (red[0] + red[1] + red[2] + red[3]) * (1.0f / 512.0f);
    __syncthreads();
    float f = rsqrtf(msh + 1e-6f);
    kv_c_norm[(size_t)row * 512 + tid]       = v0 * f * w[tid];
    kv_c_norm[(size_t)row * 512 + tid + 256] = v1 * f * w[tid + 256];
    if (tid < 32) {
        int pos = row & (SEQ - 1);
        float c = table[pos*64 + tid], s = table[pos*64 + 32 + tid];
        float x1 = src[512 + tid], x2 = src[512 + 32 + tid];
        k_rope_out[(size_t)row * 64 + tid]      = x1*c - x2*s;
        k_rope_out[(size_t)row * 64 + 32 + tid] = x2*c + x1*s;
    }
}

// ---------------- RoPE on q (in place) ----------------
__global__ __launch_bounds__(256) void q_rope_kernel(float* __restrict__ q,
                                                     const float* __restrict__ table) {
    int g = blockIdx.x * 8 + (threadIdx.x >> 5);  // (row,h) pair id, < 65536
    int i = threadIdx.x & 31;
    int row = g >> 4, h = g & 15;
    size_t base = (size_t)row * (NH*HD) + h * HD + D_NOPE;
    int pos = row & (SEQ - 1);
    float c = table[pos*64 + i], s = table[pos*64 + 32 + i];
    float x1 = q[base + i], x2 = q[base + 32 + i];
    q[base + i]      = x1*c - x2*s;
    q[base + 32 + i] = x2*c + x1*s;
}

// ---------------- flash attention (causal, online softmax) ----------------
// grid (S/32, H, B), 256 threads. 8 lanes per q-row; 32 q-rows per block.
// Per-lane hot state: qreg[24] + o[16] + p[16] ~= 56 VGPRs -> no spill.
__global__ __launch_bounds__(256, 4) void flash_kernel(
    const float* __restrict__ q,       // (4096, 3072) roped
    const float* __restrict__ kv_exp,  // (4096, 4096)  per head: [k_nope 128 | v 128]
    const float* __restrict__ k_rope,  // (4096, 64) roped
    float* __restrict__ attn_out)      // (4096, 2048)
{
    const int qb  = blockIdx.x;   // 0..63
    const int h   = blockIdx.y;   // 0..15
    const int bb  = blockIdx.z;   // 0..1
    const int tid = threadIdx.x;
    const int r   = tid >> 3;     // q-row within tile (0..31)
    const int tx  = tid & 7;      // lane-in-row: 24-wide slice of head dim

    const int q0 = qb * 32;
    const int row_base = bb * SEQ;
    const int qrow = q0 + r;
    const int qtok = row_base + qrow;

    __shared__ float Ks[32][192];  // 24KB  [k_nope | k_rope]
    __shared__ float Vs[32][128];  // 16KB

    float qreg[24];
    {
        const float* qp = q + (size_t)qtok * (NH*HD) + h * HD + tx * 24;
        #pragma unroll
        for (int j = 0; j < 6; j++) {
            float4 v = *(const float4*)(qp + j * 4);
            qreg[j*4+0]=v.x; qreg[j*4+1]=v.y; qreg[j*4+2]=v.z; qreg[j*4+3]=v.w;
        }
    }

    float o[16];
    #pragma unroll
    for (int j = 0; j < 16; j++) o[j] = 0.f;
    float m = -INFINITY, l = 0.f;

    const float scale = 0.07216878364870322f;  // 1/sqrt(192)
    const int nkb = qb + 1;   // 32-key blocks covering keys <= q0+31

    for (int kb = 0; kb < nkb; kb++) {
        const int k0 = kb * 32;
        __syncthreads();   // previous iteration's LDS reads done
        // stage K_nope + V
        {
            const float4* src = (const float4*)(kv_exp + (size_t)(row_base + k0) * 4096 + h * 256);
            #pragma unroll
            for (int t = 0; t < 8; t++) {
                int s = tid + t * 256;      // 0..2047
                int c = s >> 6, f = s & 63;
                float4 v = src[(size_t)c * 1024 + f];
                if (f < 32) *((float4*)&Ks[c][f*4]) = v;
                else        *((float4*)&Vs[c][(f-32)*4]) = v;
            }
            const float4* rsrc = (const float4*)(k_rope + (size_t)(row_base + k0) * 64);
            #pragma unroll
            for (int t = 0; t < 2; t++) {
                int s = tid + t * 256;      // 0..511
                int c = s >> 4, f = s & 15;
                *((float4*)&Ks[c][128 + f*4]) = rsrc[c * 16 + f];
            }
        }
        __syncthreads();

        // two 16-key passes to keep p[] small
        #pragma unroll
        for (int half = 0; half < 2; half++) {
            const int cbase = half * 16;
            float p[16];
            #pragma unroll
            for (int c = 0; c < 16; c++) {
                float acc = 0.f;
                const float* kp = &Ks[cbase + c][tx * 24];
                #pragma unroll
                for (int j = 0; j < 24; j++) acc += qreg[j] * kp[j];
                p[c] = acc;
            }
            #pragma unroll
            for (int c = 0; c < 16; c++) {
                p[c] += __shfl_xor(p[c], 1);
                p[c] += __shfl_xor(p[c], 2);
                p[c] += __shfl_xor(p[c], 4);
            }
            float mnew = m;
            #pragma unroll
            for (int c = 0; c < 16; c++) {
                float sc = (k0 + cbase + c <= qrow) ? p[c] * scale : -INFINITY;
                p[c] = sc;
                mnew = fmaxf(mnew, sc);
            }
            float alpha = __expf(m - mnew);
            float ps = 0.f;
            #pragma unroll
            for (int c = 0; c < 16; c++) {
                float e = __expf(p[c] - mnew);
                p[c] = e;
                ps += e;
            }
            l = l * alpha + ps;
            m = mnew;
            #pragma unroll
            for (int j = 0; j < 16; j++) o[j] *= alpha;
            // o += p @ V  (chunk order rotated so conflicting lanes pair 2-way)
            #pragma unroll
            for (int c = 0; c < 16; c++) {
                float pc = p[c];
                const float4* vrow = (const float4*)&Vs[cbase + c][tx * 16];
                #pragma unroll
                for (int jj = 0; jj < 4; jj++) {
                    int ch = (jj + tx) & 3;
                    float4 v = vrow[ch];
                    o[ch*4+0] += pc * v.x; o[ch*4+1] += pc * v.y;
                    o[ch*4+2] += pc * v.z; o[ch*4+3] += pc * v.w;
                }
            }
        }
    }

    float inv_l = 1.0f / l;
    float* op = attn_out + (size_t)qtok * (NH*V_DIM) + h * V_DIM + tx * 16;
    #pragma unroll
    for (int ch = 0; ch < 4; ch++) {
        float4 v = make_float4(o[ch*4+0]*inv_l, o[ch*4+1]*inv_l,
                               o[ch*4+2]*inv_l, o[ch*4+3]*inv_l);
        *((float4*)(op + ch * 4)) = v;
    }
}

// ---------------- launch ----------------
extern "C" void kernel_launch(void* const* d_in, const int* in_sizes, int n_in,
                              void* d_out, int out_size, void* d_ws, size_t ws_size,
                              hipStream_t stream)
{
    const float* x         = (const float*)d_in[0];  // (2,2048,2048)
    const float* w_q_down  = (const float*)d_in[1];  // (2048,1536)
    const float* w_q_up    = (const float*)d_in[2];  // (1536,3072)
    const float* w_kv_down = (const float*)d_in[3];  // (2048,576)
    const float* kv_norm_w = (const float*)d_in[4];  // (512,)
    const float* w_kv_up   = (const float*)d_in[5];  // (512,4096)
    const float* w_out     = (const float*)d_in[6];  // (2048,2048)
    float* out = (float*)d_out;                      // (2,2048,2048)
    float* ws  = (float*)d_ws;

    // workspace layout (float offsets)
    float* table   = ws;              //  131072
    float* q_down  = ws + 131072;     // 4096*1536
    float* q       = ws + 6422528;    // 4096*3072
    float* kv_full = ws + 19005440;   // 4096*576
    float* kv_c    = ws + 21364736;   // 4096*512
    float* kv_exp  = ws + 23461888;   // 4096*4096
    float* k_rope  = ws + 40239104;   // 4096*64
    float* attn    = ws + 40501248;   // 4096*2048
    // total = 48889856 floats = ~186.5 MB

    rope_table_kernel<<<512, 256, 0, stream>>>(table);

    sgemm_kernel<<<dim3(1536/64, ROWS/128), 256, 0, stream>>>(x, w_q_down, q_down, ROWS, 1536, 2048);
    sgemm_kernel<<<dim3(3072/64, ROWS/128), 256, 0, stream>>>(q_down, w_q_up, q, ROWS, 3072, 1536);
    sgemm_kernel<<<dim3(576/64, ROWS/128), 256, 0, stream>>>(x, w_kv_down, kv_full, ROWS, 576, 2048);
    kv_norm_rope_kernel<<<ROWS, 256, 0, stream>>>(kv_full, kv_norm_w, table, kv_c, k_rope);
    sgemm_kernel<<<dim3(4096/64, ROWS/128), 256, 0, stream>>>(kv_c, w_kv_up, kv_exp, ROWS, 4096, 512);
    q_rope_kernel<<<8192, 256, 0, stream>>>(q, table);
    flash_kernel<<<dim3(SEQ/32, NH, BATCH), 256, 0, stream>>>(q, kv_exp, k_rope, attn);
    sgemm_kernel<<<dim3(2048/64, ROWS/128), 256, 0, stream>>>(attn, w_out, out, ROWS, 2048, 2048);
}

// Round 3
// 2549.612 us; speedup vs baseline: 16.0718x; 10.8512x over previous
//
#include <hip/hip_runtime.h>
#include <hip/hip_bf16.h>
#include <math.h>

// ---------------- problem constants ----------------
#define HID    2048
#define NH     16
#define D_NOPE 128
#define D_ROPE 64
#define HD     192      // HEAD_DIM
#define V_DIM  128
#define KV_RANK 512
#define Q_RANK  1536
#define BATCH  2
#define SEQ    2048
#define ROWS   (BATCH*SEQ)   // 4096

typedef __attribute__((ext_vector_type(8))) short short8;
typedef __attribute__((ext_vector_type(4))) float f32x4;

__device__ __forceinline__ unsigned short f2bf(float x) {
    unsigned int u = __float_as_uint(x);
    unsigned int r = (u + 0x7fffu + ((u >> 16) & 1u)) >> 16;
    return (unsigned short)r;
}

// ---------------- RoPE cos/sin table ----------------
__global__ void rope_table_kernel(float* __restrict__ table) {
    int idx = blockIdx.x * 256 + threadIdx.x;   // < 2048*64 = 131072
    int pos = idx >> 6, u = idx & 63;
    int i = u & 31;
    float invf = expf((float)i * (-9.210340371976184f / 32.0f));
    float ang = (float)pos * invf;
    table[idx] = (u < 32) ? cosf(ang) : sinf(ang);
}

// ---------------- generic fp32 GEMM (unchanged, proven) ----------------
__global__ __launch_bounds__(256) void sgemm_kernel(
    const float* __restrict__ A, const float* __restrict__ B, float* __restrict__ C,
    int M, int N, int K)
{
    const int tid = threadIdx.x;
    const int tx = tid & 15;
    const int ty = tid >> 4;
    const int n0 = blockIdx.x * 64;
    const int m0 = blockIdx.y * 128;

    __shared__ float As[16][136];
    __shared__ float Bs[16][64];

    float acc[8][4] = {};

    for (int k0 = 0; k0 < K; k0 += 16) {
        #pragma unroll
        for (int t = 0; t < 2; t++) {
            int s = tid + t * 256;
            int row = s >> 2, kc = s & 3;
            float4 v = *(const float4*)(A + (size_t)(m0 + row) * K + k0 + kc * 4);
            As[kc*4+0][row] = v.x;
            As[kc*4+1][row] = v.y;
            As[kc*4+2][row] = v.z;
            As[kc*4+3][row] = v.w;
        }
        {
            int krow = tid >> 4, nc = tid & 15;
            float4 v = *(const float4*)(B + (size_t)(k0 + krow) * N + n0 + nc * 4);
            *((float4*)&Bs[krow][nc*4]) = v;
        }
        __syncthreads();

        #pragma unroll
        for (int kk = 0; kk < 16; kk++) {
            float4 a0 = *(const float4*)&As[kk][ty*8];
            float4 a1 = *(const float4*)&As[kk][ty*8+4];
            float4 b  = *(const float4*)&Bs[kk][tx*4];
            float av[8] = {a0.x,a0.y,a0.z,a0.w,a1.x,a1.y,a1.z,a1.w};
            #pragma unroll
            for (int i = 0; i < 8; i++) {
                acc[i][0] += av[i]*b.x; acc[i][1] += av[i]*b.y;
                acc[i][2] += av[i]*b.z; acc[i][3] += av[i]*b.w;
            }
        }
        __syncthreads();
    }

    #pragma unroll
    for (int i = 0; i < 8; i++) {
        float4 v = make_float4(acc[i][0], acc[i][1], acc[i][2], acc[i][3]);
        *((float4*)(C + (size_t)(m0 + ty*8 + i) * N + n0 + tx*4)) = v;
    }
}

// ---------------- RMSNorm(kv_c) + RoPE(k_rope) ----------------
__global__ __launch_bounds__(256) void kv_norm_rope_kernel(
    const float* __restrict__ kv_full,   // (4096, 576)
    const float* __restrict__ w,         // (512,)
    const float* __restrict__ table,
    float* __restrict__ kv_c_norm,       // (4096, 512)
    float* __restrict__ k_rope_out)      // (4096, 64)
{
    const int row = blockIdx.x;
    const int tid = threadIdx.x;
    const float* src = kv_full + (size_t)row * 576;
    float v0 = src[tid], v1 = src[tid + 256];
    float ss = v0*v0 + v1*v1;
    #pragma unroll
    for (int off = 32; off > 0; off >>= 1) ss += __shfl_down(ss, off);
    __shared__ float red[4];
    __shared__ float msh;
    if ((tid & 63) == 0) red[tid >> 6] = ss;
    __syncthreads();
    if (tid == 0) msh = (red[0] + red[1] + red[2] + red[3]) * (1.0f / 512.0f);
    __syncthreads();
    float f = rsqrtf(msh + 1e-6f);
    kv_c_norm[(size_t)row * 512 + tid]       = v0 * f * w[tid];
    kv_c_norm[(size_t)row * 512 + tid + 256] = v1 * f * w[tid + 256];
    if (tid < 32) {
        int pos = row & (SEQ - 1);
        float c = table[pos*64 + tid], s = table[pos*64 + 32 + tid];
        float x1 = src[512 + tid], x2 = src[512 + 32 + tid];
        k_rope_out[(size_t)row * 64 + tid]      = x1*c - x2*s;
        k_rope_out[(size_t)row * 64 + 32 + tid] = x2*c + x1*s;
    }
}

// ---------------- RoPE on q (in place) ----------------
__global__ __launch_bounds__(256) void q_rope_kernel(float* __restrict__ q,
                                                     const float* __restrict__ table) {
    int g = blockIdx.x * 8 + (threadIdx.x >> 5);  // (row,h) pair id, < 65536
    int i = threadIdx.x & 31;
    int row = g >> 4, h = g & 15;
    size_t base = (size_t)row * (NH*HD) + h * HD + D_NOPE;
    int pos = row & (SEQ - 1);
    float c = table[pos*64 + i], s = table[pos*64 + 32 + i];
    float x1 = q[base + i], x2 = q[base + 32 + i];
    q[base + i]      = x1*c - x2*s;
    q[base + 32 + i] = x2*c + x1*s;
}

// ---------------- pack q (roped, fp32) -> Qmat bf16 [b][h][s][192] ----------
__global__ __launch_bounds__(256) void pack_q_kernel(
    const float* __restrict__ q, unsigned short* __restrict__ Qmat)
{
    int wid = blockIdx.x * 4 + (threadIdx.x >> 6);   // 0..65535
    int lane = threadIdx.x & 63;
    int row = wid >> 4, h = wid & 15;
    int b = row >> 11, s = row & (SEQ-1);
    const float* src = q + (size_t)row * (NH*HD) + h * HD;
    unsigned short* dst = Qmat + ((size_t)(b*NH + h) * SEQ + s) * HD;
    dst[lane]       = f2bf(src[lane]);
    dst[lane + 64]  = f2bf(src[lane + 64]);
    dst[lane + 128] = f2bf(src[lane + 128]);
}

// ---------------- pack K: kv_exp k_nope + roped k_rope -> Kmat bf16 --------
__global__ __launch_bounds__(256) void pack_k_kernel(
    const float* __restrict__ kv_exp,   // (4096, 4096)
    const float* __restrict__ k_rope,   // (4096, 64) roped
    unsigned short* __restrict__ Kmat)  // [b][h][s][192]
{
    int wid = blockIdx.x * 4 + (threadIdx.x >> 6);   // 0..65535
    int lane = threadIdx.x & 63;
    int row = wid >> 4, h = wid & 15;
    int b = row >> 11, s = row & (SEQ-1);
    const float* src = kv_exp + (size_t)row * 4096 + h * 256;
    unsigned short* dst = Kmat + ((size_t)(b*NH + h) * SEQ + s) * HD;
    dst[lane]       = f2bf(src[lane]);
    dst[lane + 64]  = f2bf(src[lane + 64]);
    dst[lane + 128] = f2bf(k_rope[(size_t)row * 64 + lane]);
}

// ---------------- pack V transposed: kv_exp v -> Vmat bf16 [b][h][128][s] --
__global__ __launch_bounds__(256) void pack_vt_kernel(
    const float* __restrict__ kv_exp, unsigned short* __restrict__ Vmat)
{
    const int st = blockIdx.x;     // 32 tiles of 64 tokens
    const int h  = blockIdx.y;
    const int b  = blockIdx.z;
    const int tid = threadIdx.x;
    const int s0 = st * 64;
    __shared__ float T[64][129];

    #pragma unroll
    for (int t = 0; t < 8; t++) {
        int idx = tid + t * 256;            // 0..2047 float4 slots
        int tokr = idx >> 5, c4 = idx & 31;
        float4 v = *(const float4*)(kv_exp + ((size_t)(b*SEQ) + s0 + tokr) * 4096 + h*256 + 128 + c4*4);
        T[tokr][c4*4+0] = v.x; T[tokr][c4*4+1] = v.y;
        T[tokr][c4*4+2] = v.z; T[tokr][c4*4+3] = v.w;
    }
    __syncthreads();

    int d = tid >> 1, sh = (tid & 1) * 32;
    unsigned short* op = Vmat + ((size_t)((b*NH + h) * V_DIM + d)) * SEQ + s0 + sh;
    #pragma unroll
    for (int j = 0; j < 32; j += 2) {
        ushort2 u;
        u.x = f2bf(T[sh + j][d]);
        u.y = f2bf(T[sh + j + 1][d]);
        *(ushort2*)(op + j) = u;
    }
}

// ---------------- MFMA flash attention ----------------
// grid (S/64, H, B), 256 threads = 4 independent waves; wave w: 16 q-rows.
// No barriers: K/V fragments from global (L1-shared), P roundtrip in
// per-wave LDS (80B-stride rows -> conflict-free b128 A-frag reads).
__global__ __launch_bounds__(256, 4) void flash_mfma_kernel(
    const unsigned short* __restrict__ Qmat,  // [b][h][s][192]
    const unsigned short* __restrict__ Kmat,  // [b][h][s][192]
    const unsigned short* __restrict__ Vmat,  // [b][h][128][s]
    float* __restrict__ attn_out)             // (4096, 2048)
{
    const int qb  = blockIdx.x;   // 0..31
    const int h   = blockIdx.y;
    const int b   = blockIdx.z;
    const int tid  = threadIdx.x;
    const int w    = tid >> 6;
    const int lane = tid & 63;
    const int n16  = lane & 15;
    const int quad = lane >> 4;

    const int q0 = qb * 64 + w * 16;               // wave's first q-row (in seq)
    const size_t bh = (size_t)(b * NH + h);
    const unsigned short* qbase = Qmat + bh * SEQ * HD;
    const unsigned short* kbase = Kmat + bh * SEQ * HD;
    const unsigned short* vbase = Vmat + bh * V_DIM * SEQ;

    __shared__ unsigned short Plds[4][16][40];     // per-wave P tile (pad->80B rows)

    // Q fragments: A[m=lane&15][k=quad*8+j], 6 chunks of K=32
    short8 qf[6];
    {
        const unsigned short* qp = qbase + (size_t)(q0 + n16) * HD + quad * 8;
        #pragma unroll
        for (int kc = 0; kc < 6; kc++)
            qf[kc] = *(const short8*)(qp + kc * 32);
    }

    f32x4 O[8];
    #pragma unroll
    for (int c = 0; c < 8; c++) O[c] = (f32x4){0.f, 0.f, 0.f, 0.f};
    float mrow[4] = {-INFINITY, -INFINITY, -INFINITY, -INFINITY};
    float lrow[4] = {0.f, 0.f, 0.f, 0.f};

    const float scale = 0.07216878364870322f;      // 1/sqrt(192)
    const int ntiles = (q0 + 16 + 31) >> 5;        // keys <= q0+15 covered

    for (int kt = 0; kt < ntiles; kt++) {
        const int k0 = kt * 32;

        // ---- QK^T: two 16-key halves, 6 K-chunks each ----
        f32x4 S[2];
        #pragma unroll
        for (int half = 0; half < 2; half++) {
            f32x4 acc = (f32x4){0.f, 0.f, 0.f, 0.f};
            const unsigned short* kp = kbase + (size_t)(k0 + half*16 + n16) * HD + quad * 8;
            #pragma unroll
            for (int kc = 0; kc < 6; kc++) {
                short8 kf = *(const short8*)(kp + kc * 32);
                acc = __builtin_amdgcn_mfma_f32_16x16x32_bf16(qf[kc], kf, acc, 0, 0, 0);
            }
            S[half] = acc;
        }

        // ---- online softmax in C-layout (row=quad*4+r, col=lane&15) ----
        float p0[4], p1[4], mnew[4];
        #pragma unroll
        for (int r = 0; r < 4; r++) {
            int row = q0 + quad*4 + r;
            float s0v = (k0 + n16      <= row) ? S[0][r] * scale : -INFINITY;
            float s1v = (k0 + 16 + n16 <= row) ? S[1][r] * scale : -INFINITY;
            p0[r] = s0v; p1[r] = s1v;
            float t = fmaxf(s0v, s1v);
            t = fmaxf(t, __shfl_xor(t, 1));
            t = fmaxf(t, __shfl_xor(t, 2));
            t = fmaxf(t, __shfl_xor(t, 4));
            t = fmaxf(t, __shfl_xor(t, 8));
            mnew[r] = fmaxf(mrow[r], t);
        }
        #pragma unroll
        for (int r = 0; r < 4; r++) {
            float alpha = __expf(mrow[r] - mnew[r]);
            float e0 = __expf(p0[r] - mnew[r]);
            float e1 = __expf(p1[r] - mnew[r]);
            float ps = e0 + e1;
            ps += __shfl_xor(ps, 1);
            ps += __shfl_xor(ps, 2);
            ps += __shfl_xor(ps, 4);
            ps += __shfl_xor(ps, 8);
            lrow[r] = lrow[r] * alpha + ps;
            mrow[r] = mnew[r];
            #pragma unroll
            for (int c = 0; c < 8; c++) O[c][r] *= alpha;
            unsigned short* pw = &Plds[w][quad*4 + r][0];
            pw[n16]      = f2bf(e0);
            pw[16 + n16] = f2bf(e1);
        }

        // ---- P as A-frag (per-wave LDS roundtrip), then PV ----
        short8 pf = *(const short8*)(&Plds[w][n16][quad * 8]);
        const unsigned short* vp = vbase + (size_t)n16 * SEQ + k0 + quad * 8;
        #pragma unroll
        for (int c = 0; c < 8; c++) {
            short8 vf = *(const short8*)(vp + (size_t)(c * 16) * SEQ);
            O[c] = __builtin_amdgcn_mfma_f32_16x16x32_bf16(pf, vf, O[c], 0, 0, 0);
        }
    }

    // ---- epilogue: O/l -> attn ----
    float invl[4];
    #pragma unroll
    for (int r = 0; r < 4; r++) invl[r] = 1.0f / lrow[r];
    #pragma unroll
    for (int c = 0; c < 8; c++) {
        #pragma unroll
        for (int r = 0; r < 4; r++) {
            size_t tok = (size_t)b * SEQ + q0 + quad*4 + r;
            attn_out[tok * (NH*V_DIM) + h * V_DIM + c*16 + n16] = O[c][r] * invl[r];
        }
    }
}

// ---------------- launch ----------------
extern "C" void kernel_launch(void* const* d_in, const int* in_sizes, int n_in,
                              void* d_out, int out_size, void* d_ws, size_t ws_size,
                              hipStream_t stream)
{
    const float* x         = (const float*)d_in[0];
    const float* w_q_down  = (const float*)d_in[1];
    const float* w_q_up    = (const float*)d_in[2];
    const float* w_kv_down = (const float*)d_in[3];
    const float* kv_norm_w = (const float*)d_in[4];
    const float* w_kv_up   = (const float*)d_in[5];
    const float* w_out     = (const float*)d_in[6];
    float* out = (float*)d_out;
    float* ws  = (float*)d_ws;

    // workspace layout (float offsets) — bf16 packs overlay dead regions
    float* table   = ws;              //  131072
    float* q_down  = ws + 131072;     // 4096*1536 (dead after gemm2 -> Qmat)
    float* q       = ws + 6422528;    // 4096*3072 (dead after pack_q -> Kmat+Vmat)
    float* kv_full = ws + 19005440;   // 4096*576
    float* kv_c    = ws + 21364736;   // 4096*512
    float* kv_exp  = ws + 23461888;   // 4096*4096
    float* k_rope  = ws + 40239104;   // 4096*64
    float* attn    = ws + 40501248;   // 4096*2048
    unsigned short* Qmat = (unsigned short*)(ws + 131072);    // 12.6M bf16 (= q_down size)
    unsigned short* Kmat = (unsigned short*)(ws + 6422528);   // 12.6M bf16
    unsigned short* Vmat = (unsigned short*)(ws + 12713984);  // 8.4M bf16 (ends < 19005440)

    rope_table_kernel<<<512, 256, 0, stream>>>(table);

    sgemm_kernel<<<dim3(1536/64, ROWS/128), 256, 0, stream>>>(x, w_q_down, q_down, ROWS, 1536, 2048);
    sgemm_kernel<<<dim3(3072/64, ROWS/128), 256, 0, stream>>>(q_down, w_q_up, q, ROWS, 3072, 1536);
    q_rope_kernel<<<8192, 256, 0, stream>>>(q, table);
    pack_q_kernel<<<16384, 256, 0, stream>>>(q, Qmat);

    sgemm_kernel<<<dim3(576/64, ROWS/128), 256, 0, stream>>>(x, w_kv_down, kv_full, ROWS, 576, 2048);
    kv_norm_rope_kernel<<<ROWS, 256, 0, stream>>>(kv_full, kv_norm_w, table, kv_c, k_rope);
    sgemm_kernel<<<dim3(4096/64, ROWS/128), 256, 0, stream>>>(kv_c, w_kv_up, kv_exp, ROWS, 4096, 512);
    pack_k_kernel<<<16384, 256, 0, stream>>>(kv_exp, k_rope, Kmat);
    pack_vt_kernel<<<dim3(SEQ/64, NH, BATCH), 256, 0, stream>>>(kv_exp, Vmat);

    flash_mfma_kernel<<<dim3(SEQ/64, NH, BATCH), 256, 0, stream>>>(Qmat, Kmat, Vmat, attn);

    sgemm_kernel<<<dim3(2048/64, ROWS/128), 256, 0, stream>>>(attn, w_out, out, ROWS, 2048, 2048);
}

// Round 4
// 966.165 us; speedup vs baseline: 42.4119x; 2.6389x over previous
//
#include <hip/hip_runtime.h>
#include <hip/hip_bf16.h>
#include <math.h>

// ---------------- problem constants ----------------
#define HID    2048
#define NH     16
#define D_NOPE 128
#define D_ROPE 64
#define HD     192      // HEAD_DIM
#define V_DIM  128
#define KV_RANK 512
#define Q_RANK  1536
#define BATCH  2
#define SEQ    2048
#define ROWS   (BATCH*SEQ)   // 4096

typedef __attribute__((ext_vector_type(8))) short short8;
typedef __attribute__((ext_vector_type(4))) float f32x4;

__device__ __forceinline__ unsigned short f2bf(float x) {
    unsigned int u = __float_as_uint(x);
    unsigned int r = (u + 0x7fffu + ((u >> 16) & 1u)) >> 16;
    return (unsigned short)r;
}

typedef const __attribute__((address_space(1))) unsigned int gu32;
typedef __attribute__((address_space(3))) unsigned int lu32;
__device__ __forceinline__ void gl_lds16(const void* g, void* l) {
    __builtin_amdgcn_global_load_lds((gu32*)g, (lu32*)l, 16, 0, 0);
}

// ---------------- RoPE cos/sin table ----------------
__global__ void rope_table_kernel(float* __restrict__ table) {
    int idx = blockIdx.x * 256 + threadIdx.x;   // < 2048*64
    int pos = idx >> 6, u = idx & 63;
    int i = u & 31;
    float invf = expf((float)i * (-9.210340371976184f / 32.0f));
    float ang = (float)pos * invf;
    table[idx] = (u < 32) ? cosf(ang) : sinf(ang);
}

// ---------------- fp32 -> bf16 elementwise ----------------
__global__ __launch_bounds__(256) void convert_bf16_kernel(
    const float* __restrict__ src, unsigned short* __restrict__ dst)
{
    size_t i = (size_t)(blockIdx.x * 256 + threadIdx.x) * 4;
    float4 v = *(const float4*)(src + i);
    ushort4 u;
    u.x = f2bf(v.x); u.y = f2bf(v.y); u.z = f2bf(v.z); u.w = f2bf(v.w);
    *(ushort4*)(dst + i) = u;
}

// ---------------- fp32 (K x N) -> bf16 transposed (N x K) ----------------
__global__ __launch_bounds__(256) void transpose_bf16_kernel(
    const float* __restrict__ src, unsigned short* __restrict__ dst, int K, int N)
{
    __shared__ float T[64][65];
    const int n0 = blockIdx.x * 64, k0 = blockIdx.y * 64;
    const int t = threadIdx.x;
    const int c4 = t & 15, r = t >> 4;   // r: 0..15
    #pragma unroll
    for (int i = 0; i < 4; i++) {
        int row = r + i * 16;
        float4 v = *(const float4*)(src + (size_t)(k0 + row) * N + n0 + c4 * 4);
        T[row][c4*4+0] = v.x; T[row][c4*4+1] = v.y;
        T[row][c4*4+2] = v.z; T[row][c4*4+3] = v.w;
    }
    __syncthreads();
    #pragma unroll
    for (int i = 0; i < 4; i++) {
        int nrow = r + i * 16;
        ushort4 u;
        u.x = f2bf(T[c4*4+0][nrow]); u.y = f2bf(T[c4*4+1][nrow]);
        u.z = f2bf(T[c4*4+2][nrow]); u.w = f2bf(T[c4*4+3][nrow]);
        *(ushort4*)(dst + (size_t)(n0 + nrow) * K + k0 + c4 * 4) = u;
    }
}

// ---------------- bf16 MFMA GEMM: C(M,N) = A(M,K) @ Bt(N,K)^T ----------------
// m97 structure: 128 x BN tile, BK=32, 4 waves x (64 x NT*16), XOR-swizzled LDS,
// global_load_lds width-16 staging.
template<int BN, bool OUT_BF16>
__global__ __launch_bounds__(256) void bgemm_kernel(
    const unsigned short* __restrict__ A,    // M x K bf16
    const unsigned short* __restrict__ Bt,   // N x K bf16
    void* __restrict__ Cv,                   // M x N (fp32 or bf16)
    int M, int N, int K)
{
    constexpr int NT = BN / 32;          // n-tiles per wave
    constexpr int NSLAB = 8 + BN / 16;   // 16-row staging slabs (A:8, B:BN/16)
    const int tid  = threadIdx.x;
    const int w    = tid >> 6;
    const int lane = tid & 63;
    const int n16  = lane & 15, quad = lane >> 4;
    const int m0 = blockIdx.y * 128;
    const int n0 = blockIdx.x * BN;
    const int moff = (w & 1) * 64;
    const int noff = (w >> 1) * (NT * 16);

    __shared__ unsigned short As[128 * 32];
    __shared__ unsigned short Bs[BN * 32];

    // staging assignment: slab s covers 16 rows; lane i -> row i>>2, stored chunk i&3
    const unsigned short* gp[4];
    unsigned short* lp[4];
    int ns = 0;
    const int rl = lane >> 2, sc = lane & 3;
    for (int s = w; s < NSLAB; s += 4) {
        int kc = sc ^ (((s * 16 + rl) >> 1) & 3);   // XOR swizzle
        if (s < 8) {
            gp[ns] = A + (size_t)(m0 + s * 16 + rl) * K + kc * 8;
            lp[ns] = As + s * 512;
        } else {
            int sb = s - 8;
            gp[ns] = Bt + (size_t)(n0 + sb * 16 + rl) * K + kc * 8;
            lp[ns] = Bs + sb * 512;
        }
        ns++;
    }

    // fragment LDS element offsets (k0-independent)
    const int swz = (quad ^ ((n16 >> 1) & 3)) * 8;
    int aoff[4], boff[NT];
    #pragma unroll
    for (int mt = 0; mt < 4; mt++) aoff[mt] = (moff + mt * 16 + n16) * 32 + swz;
    #pragma unroll
    for (int nt = 0; nt < NT; nt++) boff[nt] = (noff + nt * 16 + n16) * 32 + swz;

    f32x4 acc[4][NT];
    #pragma unroll
    for (int mt = 0; mt < 4; mt++)
        #pragma unroll
        for (int nt = 0; nt < NT; nt++) acc[mt][nt] = (f32x4){0.f, 0.f, 0.f, 0.f};

    for (int k0 = 0; k0 < K; k0 += 32) {
        #pragma unroll
        for (int j = 0; j < 4; j++) if (j < ns) gl_lds16(gp[j], lp[j]);
        #pragma unroll
        for (int j = 0; j < 4; j++) if (j < ns) gp[j] += 32;
        __syncthreads();

        short8 af[4], bfr[NT];
        #pragma unroll
        for (int mt = 0; mt < 4; mt++) af[mt] = *(const short8*)(As + aoff[mt]);
        #pragma unroll
        for (int nt = 0; nt < NT; nt++) bfr[nt] = *(const short8*)(Bs + boff[nt]);
        #pragma unroll
        for (int mt = 0; mt < 4; mt++)
            #pragma unroll
            for (int nt = 0; nt < NT; nt++)
                acc[mt][nt] = __builtin_amdgcn_mfma_f32_16x16x32_bf16(
                    af[mt], bfr[nt], acc[mt][nt], 0, 0, 0);
        __syncthreads();
    }

    // epilogue: C[row=quad*4+r][col=n16] per 16x16 tile
    #pragma unroll
    for (int mt = 0; mt < 4; mt++)
        #pragma unroll
        for (int nt = 0; nt < NT; nt++)
            #pragma unroll
            for (int r = 0; r < 4; r++) {
                size_t idx = (size_t)(m0 + moff + mt * 16 + quad * 4 + r) * N
                           + n0 + noff + nt * 16 + n16;
                if (OUT_BF16) ((unsigned short*)Cv)[idx] = f2bf(acc[mt][nt][r]);
                else          ((float*)Cv)[idx] = acc[mt][nt][r];
            }
}

// ---------------- RMSNorm(kv_c)->bf16 + RoPE(k_rope) ----------------
__global__ __launch_bounds__(256) void kv_norm_rope_kernel(
    const float* __restrict__ kv_full,   // (4096, 576)
    const float* __restrict__ w,         // (512,)
    const float* __restrict__ table,
    unsigned short* __restrict__ kv_cb,  // (4096, 512) bf16
    float* __restrict__ k_rope_out)      // (4096, 64)
{
    const int row = blockIdx.x;
    const int tid = threadIdx.x;
    const float* src = kv_full + (size_t)row * 576;
    float v0 = src[tid], v1 = src[tid + 256];
    float ss = v0*v0 + v1*v1;
    #pragma unroll
    for (int off = 32; off > 0; off >>= 1) ss += __shfl_down(ss, off);
    __shared__ float red[4];
    __shared__ float msh;
    if ((tid & 63) == 0) red[tid >> 6] = ss;
    __syncthreads();
    if (tid == 0) msh = (red[0] + red[1] + red[2] + red[3]) * (1.0f / 512.0f);
    __syncthreads();
    float f = rsqrtf(msh + 1e-6f);
    kv_cb[(size_t)row * 512 + tid]       = f2bf(v0 * f * w[tid]);
    kv_cb[(size_t)row * 512 + tid + 256] = f2bf(v1 * f * w[tid + 256]);
    if (tid < 32) {
        int pos = row & (SEQ - 1);
        float c = table[pos*64 + tid], s = table[pos*64 + 32 + tid];
        float x1 = src[512 + tid], x2 = src[512 + 32 + tid];
        k_rope_out[(size_t)row * 64 + tid]      = x1*c - x2*s;
        k_rope_out[(size_t)row * 64 + 32 + tid] = x2*c + x1*s;
    }
}

// ---------------- RoPE on q (in place, fp32) ----------------
__global__ __launch_bounds__(256) void q_rope_kernel(float* __restrict__ q,
                                                     const float* __restrict__ table) {
    int g = blockIdx.x * 8 + (threadIdx.x >> 5);  // (row,h) pair id
    int i = threadIdx.x & 31;
    int row = g >> 4, h = g & 15;
    size_t base = (size_t)row * (NH*HD) + h * HD + D_NOPE;
    int pos = row & (SEQ - 1);
    float c = table[pos*64 + i], s = table[pos*64 + 32 + i];
    float x1 = q[base + i], x2 = q[base + 32 + i];
    q[base + i]      = x1*c - x2*s;
    q[base + 32 + i] = x2*c + x1*s;
}

// ---------------- pack q (roped, fp32) -> Qmat bf16 [b][h][s][192] ----------
__global__ __launch_bounds__(256) void pack_q_kernel(
    const float* __restrict__ q, unsigned short* __restrict__ Qmat)
{
    int wid = blockIdx.x * 4 + (threadIdx.x >> 6);
    int lane = threadIdx.x & 63;
    int row = wid >> 4, h = wid & 15;
    int b = row >> 11, s = row & (SEQ-1);
    const float* src = q + (size_t)row * (NH*HD) + h * HD;
    unsigned short* dst = Qmat + ((size_t)(b*NH + h) * SEQ + s) * HD;
    dst[lane]       = f2bf(src[lane]);
    dst[lane + 64]  = f2bf(src[lane + 64]);
    dst[lane + 128] = f2bf(src[lane + 128]);
}

// ---------------- pack K: kv_exp k_nope + roped k_rope -> Kmat bf16 --------
__global__ __launch_bounds__(256) void pack_k_kernel(
    const float* __restrict__ kv_exp,   // (4096, 4096)
    const float* __restrict__ k_rope,   // (4096, 64) roped
    unsigned short* __restrict__ Kmat)  // [b][h][s][192]
{
    int wid = blockIdx.x * 4 + (threadIdx.x >> 6);
    int lane = threadIdx.x & 63;
    int row = wid >> 4, h = wid & 15;
    int b = row >> 11, s = row & (SEQ-1);
    const float* src = kv_exp + (size_t)row * 4096 + h * 256;
    unsigned short* dst = Kmat + ((size_t)(b*NH + h) * SEQ + s) * HD;
    dst[lane]       = f2bf(src[lane]);
    dst[lane + 64]  = f2bf(src[lane + 64]);
    dst[lane + 128] = f2bf(k_rope[(size_t)row * 64 + lane]);
}

// ---------------- pack V transposed: kv_exp v -> Vmat bf16 [b][h][128][s] --
__global__ __launch_bounds__(256) void pack_vt_kernel(
    const float* __restrict__ kv_exp, unsigned short* __restrict__ Vmat)
{
    const int st = blockIdx.x;
    const int h  = blockIdx.y;
    const int b  = blockIdx.z;
    const int tid = threadIdx.x;
    const int s0 = st * 64;
    __shared__ float T[64][129];

    #pragma unroll
    for (int t = 0; t < 8; t++) {
        int idx = tid + t * 256;
        int tokr = idx >> 5, c4 = idx & 31;
        float4 v = *(const float4*)(kv_exp + ((size_t)(b*SEQ) + s0 + tokr) * 4096 + h*256 + 128 + c4*4);
        T[tokr][c4*4+0] = v.x; T[tokr][c4*4+1] = v.y;
        T[tokr][c4*4+2] = v.z; T[tokr][c4*4+3] = v.w;
    }
    __syncthreads();

    int d = tid >> 1, sh = (tid & 1) * 32;
    unsigned short* op = Vmat + ((size_t)((b*NH + h) * V_DIM + d)) * SEQ + s0 + sh;
    #pragma unroll
    for (int j = 0; j < 32; j += 2) {
        ushort2 u;
        u.x = f2bf(T[sh + j][d]);
        u.y = f2bf(T[sh + j + 1][d]);
        *(ushort2*)(op + j) = u;
    }
}

// ---------------- MFMA flash attention (out: bf16 attn) ----------------
__global__ __launch_bounds__(256, 4) void flash_mfma_kernel(
    const unsigned short* __restrict__ Qmat,  // [b][h][s][192]
    const unsigned short* __restrict__ Kmat,  // [b][h][s][192]
    const unsigned short* __restrict__ Vmat,  // [b][h][128][s]
    unsigned short* __restrict__ attnb)       // (4096, 2048) bf16
{
    const int qb  = blockIdx.x;
    const int h   = blockIdx.y;
    const int b   = blockIdx.z;
    const int tid  = threadIdx.x;
    const int w    = tid >> 6;
    const int lane = tid & 63;
    const int n16  = lane & 15;
    const int quad = lane >> 4;

    const int q0 = qb * 64 + w * 16;
    const size_t bh = (size_t)(b * NH + h);
    const unsigned short* qbase = Qmat + bh * SEQ * HD;
    const unsigned short* kbase = Kmat + bh * SEQ * HD;
    const unsigned short* vbase = Vmat + bh * V_DIM * SEQ;

    __shared__ unsigned short Plds[4][16][40];

    short8 qf[6];
    {
        const unsigned short* qp = qbase + (size_t)(q0 + n16) * HD + quad * 8;
        #pragma unroll
        for (int kc = 0; kc < 6; kc++)
            qf[kc] = *(const short8*)(qp + kc * 32);
    }

    f32x4 O[8];
    #pragma unroll
    for (int c = 0; c < 8; c++) O[c] = (f32x4){0.f, 0.f, 0.f, 0.f};
    float mrow[4] = {-INFINITY, -INFINITY, -INFINITY, -INFINITY};
    float lrow[4] = {0.f, 0.f, 0.f, 0.f};

    const float scale = 0.07216878364870322f;  // 1/sqrt(192)
    const int ntiles = (q0 + 16 + 31) >> 5;

    for (int kt = 0; kt < ntiles; kt++) {
        const int k0 = kt * 32;

        f32x4 S[2];
        #pragma unroll
        for (int half = 0; half < 2; half++) {
            f32x4 acc = (f32x4){0.f, 0.f, 0.f, 0.f};
            const unsigned short* kp = kbase + (size_t)(k0 + half*16 + n16) * HD + quad * 8;
            #pragma unroll
            for (int kc = 0; kc < 6; kc++) {
                short8 kf = *(const short8*)(kp + kc * 32);
                acc = __builtin_amdgcn_mfma_f32_16x16x32_bf16(qf[kc], kf, acc, 0, 0, 0);
            }
            S[half] = acc;
        }

        float p0[4], p1[4], mnew[4];
        #pragma unroll
        for (int r = 0; r < 4; r++) {
            int row = q0 + quad*4 + r;
            float s0v = (k0 + n16      <= row) ? S[0][r] * scale : -INFINITY;
            float s1v = (k0 + 16 + n16 <= row) ? S[1][r] * scale : -INFINITY;
            p0[r] = s0v; p1[r] = s1v;
            float t = fmaxf(s0v, s1v);
            t = fmaxf(t, __shfl_xor(t, 1));
            t = fmaxf(t, __shfl_xor(t, 2));
            t = fmaxf(t, __shfl_xor(t, 4));
            t = fmaxf(t, __shfl_xor(t, 8));
            mnew[r] = fmaxf(mrow[r], t);
        }
        #pragma unroll
        for (int r = 0; r < 4; r++) {
            float alpha = __expf(mrow[r] - mnew[r]);
            float e0 = __expf(p0[r] - mnew[r]);
            float e1 = __expf(p1[r] - mnew[r]);
            float ps = e0 + e1;
            ps += __shfl_xor(ps, 1);
            ps += __shfl_xor(ps, 2);
            ps += __shfl_xor(ps, 4);
            ps += __shfl_xor(ps, 8);
            lrow[r] = lrow[r] * alpha + ps;
            mrow[r] = mnew[r];
            #pragma unroll
            for (int c = 0; c < 8; c++) O[c][r] *= alpha;
            unsigned short* pw = &Plds[w][quad*4 + r][0];
            pw[n16]      = f2bf(e0);
            pw[16 + n16] = f2bf(e1);
        }

        short8 pf = *(const short8*)(&Plds[w][n16][quad * 8]);
        const unsigned short* vp = vbase + (size_t)n16 * SEQ + k0 + quad * 8;
        #pragma unroll
        for (int c = 0; c < 8; c++) {
            short8 vf = *(const short8*)(vp + (size_t)(c * 16) * SEQ);
            O[c] = __builtin_amdgcn_mfma_f32_16x16x32_bf16(pf, vf, O[c], 0, 0, 0);
        }
    }

    float invl[4];
    #pragma unroll
    for (int r = 0; r < 4; r++) invl[r] = 1.0f / lrow[r];
    #pragma unroll
    for (int c = 0; c < 8; c++) {
        #pragma unroll
        for (int r = 0; r < 4; r++) {
            size_t tok = (size_t)b * SEQ + q0 + quad*4 + r;
            attnb[tok * (NH*V_DIM) + h * V_DIM + c*16 + n16] = f2bf(O[c][r] * invl[r]);
        }
    }
}

// ---------------- launch ----------------
extern "C" void kernel_launch(void* const* d_in, const int* in_sizes, int n_in,
                              void* d_out, int out_size, void* d_ws, size_t ws_size,
                              hipStream_t stream)
{
    const float* x         = (const float*)d_in[0];
    const float* w_q_down  = (const float*)d_in[1];
    const float* w_q_up    = (const float*)d_in[2];
    const float* w_kv_down = (const float*)d_in[3];
    const float* kv_norm_w = (const float*)d_in[4];
    const float* w_kv_up   = (const float*)d_in[5];
    const float* w_out     = (const float*)d_in[6];
    float* out = (float*)d_out;
    float* ws  = (float*)d_ws;

    // ---- workspace layout (float offsets), lifetime-overlaid, total 47.1M floats ----
    float*          table  = ws;                                      // [0, 131072)
    unsigned short* Qmat   = (unsigned short*)(ws + 131072);          // 12.58M bf16
    unsigned short* Kmat   = (unsigned short*)(ws + 6422528);         // 12.58M bf16
    unsigned short* Vmat   = (unsigned short*)(ws + 12713984);        // 8.39M bf16
    unsigned short* attnb  = (unsigned short*)(ws + 16908288);        // 8.39M bf16? (4096*2048)
    unsigned short* xb     = (unsigned short*)(ws + 19005440);        // 8.39M bf16
    float*          q      = ws + 23199744;                           // 12.58M fp32
    float*          kv_exp = ws + 19005440;                           // 16.78M fp32 = xb ∪ q
    unsigned short* wt1    = (unsigned short*)(ws + 35782656);        // 1536x2048
    unsigned short* wt2    = (unsigned short*)(ws + 37355520);        // 3072x1536
    unsigned short* wt3    = (unsigned short*)(ws + 39714816);        // 576x2048
    unsigned short* wt4    = (unsigned short*)(ws + 40304640);        // 4096x512
    unsigned short* wt5    = (unsigned short*)(ws + 41353216);        // 2048x2048
    unsigned short* qdb    = (unsigned short*)(ws + 43450368);        // 4096x1536 (dead after GEMM2)
    float*          kv_full= ws + 43450368;                           // 4096x576 (overlays qdb)
    unsigned short* kv_cb  = (unsigned short*)(ws + 45809664);        // 4096x512
    float*          k_rope = ws + 46858240;                           // 4096x64   -> end 47120384

    rope_table_kernel<<<512, 256, 0, stream>>>(table);

    // bf16 conversions / weight transposes
    convert_bf16_kernel<<<ROWS*HID/1024, 256, 0, stream>>>(x, xb);
    transpose_bf16_kernel<<<dim3(1536/64, 2048/64), 256, 0, stream>>>(w_q_down, wt1, 2048, 1536);
    transpose_bf16_kernel<<<dim3(3072/64, 1536/64), 256, 0, stream>>>(w_q_up,   wt2, 1536, 3072);
    transpose_bf16_kernel<<<dim3(576/64,  2048/64), 256, 0, stream>>>(w_kv_down,wt3, 2048, 576);
    transpose_bf16_kernel<<<dim3(4096/64,  512/64), 256, 0, stream>>>(w_kv_up,  wt4, 512, 4096);
    transpose_bf16_kernel<<<dim3(2048/64, 2048/64), 256, 0, stream>>>(w_out,    wt5, 2048, 2048);

    // q chain
    bgemm_kernel<128, true ><<<dim3(1536/128, ROWS/128), 256, 0, stream>>>(xb,  wt1, qdb, ROWS, 1536, 2048);
    bgemm_kernel<128, false><<<dim3(3072/128, ROWS/128), 256, 0, stream>>>(qdb, wt2, q,   ROWS, 3072, 1536);
    q_rope_kernel<<<8192, 256, 0, stream>>>(q, table);
    pack_q_kernel<<<16384, 256, 0, stream>>>(q, Qmat);

    // kv chain (kv_exp overlays xb∪q — both dead by GEMM4)
    bgemm_kernel<64, false><<<dim3(576/64, ROWS/128), 256, 0, stream>>>(xb, wt3, kv_full, ROWS, 576, 2048);
    kv_norm_rope_kernel<<<ROWS, 256, 0, stream>>>(kv_full, kv_norm_w, table, kv_cb, k_rope);
    bgemm_kernel<128, false><<<dim3(4096/128, ROWS/128), 256, 0, stream>>>(kv_cb, wt4, kv_exp, ROWS, 4096, 512);
    pack_k_kernel<<<16384, 256, 0, stream>>>(kv_exp, k_rope, Kmat);
    pack_vt_kernel<<<dim3(SEQ/64, NH, BATCH), 256, 0, stream>>>(kv_exp, Vmat);

    // attention
    flash_mfma_kernel<<<dim3(SEQ/64, NH, BATCH), 256, 0, stream>>>(Qmat, Kmat, Vmat, attnb);

    // output projection
    bgemm_kernel<128, false><<<dim3(2048/128, ROWS/128), 256, 0, stream>>>(attnb, wt5, out, ROWS, 2048, 2048);
}

// Round 5
// 632.275 us; speedup vs baseline: 64.8087x; 1.5281x over previous
//
#include <hip/hip_runtime.h>
#include <hip/hip_bf16.h>
#include <math.h>

// ---------------- problem constants ----------------
#define HID    2048
#define NH     16
#define D_NOPE 128
#define D_ROPE 64
#define HD     192      // HEAD_DIM
#define V_DIM  128
#define KV_RANK 512
#define Q_RANK  1536
#define BATCH  2
#define SEQ    2048
#define ROWS   (BATCH*SEQ)   // 4096

typedef __attribute__((ext_vector_type(8))) short short8;
typedef __attribute__((ext_vector_type(4))) float f32x4;

__device__ __forceinline__ unsigned short f2bf(float x) {
    unsigned int u = __float_as_uint(x);
    unsigned int r = (u + 0x7fffu + ((u >> 16) & 1u)) >> 16;
    return (unsigned short)r;
}

typedef const __attribute__((address_space(1))) unsigned int gu32;
typedef __attribute__((address_space(3))) unsigned int lu32;
__device__ __forceinline__ void gl_lds16(const void* g, void* l) {
    __builtin_amdgcn_global_load_lds((gu32*)g, (lu32*)l, 16, 0, 0);
}

// ---------------- RoPE cos/sin table ----------------
__global__ void rope_table_kernel(float* __restrict__ table) {
    int idx = blockIdx.x * 256 + threadIdx.x;   // < 2048*64
    int pos = idx >> 6, u = idx & 63;
    int i = u & 31;
    float invf = expf((float)i * (-9.210340371976184f / 32.0f));
    float ang = (float)pos * invf;
    table[idx] = (u < 32) ? cosf(ang) : sinf(ang);
}

// ---------------- fp32 -> bf16 elementwise ----------------
__global__ __launch_bounds__(256) void convert_bf16_kernel(
    const float* __restrict__ src, unsigned short* __restrict__ dst)
{
    size_t i = (size_t)(blockIdx.x * 256 + threadIdx.x) * 4;
    float4 v = *(const float4*)(src + i);
    ushort4 u;
    u.x = f2bf(v.x); u.y = f2bf(v.y); u.z = f2bf(v.z); u.w = f2bf(v.w);
    *(ushort4*)(dst + i) = u;
}

// ---------------- fp32 (K x N) -> bf16 transposed (N x K) ----------------
__global__ __launch_bounds__(256) void transpose_bf16_kernel(
    const float* __restrict__ src, unsigned short* __restrict__ dst, int K, int N)
{
    __shared__ float T[64][65];
    const int n0 = blockIdx.x * 64, k0 = blockIdx.y * 64;
    const int t = threadIdx.x;
    const int c4 = t & 15, r = t >> 4;   // r: 0..15
    #pragma unroll
    for (int i = 0; i < 4; i++) {
        int row = r + i * 16;
        float4 v = *(const float4*)(src + (size_t)(k0 + row) * N + n0 + c4 * 4);
        T[row][c4*4+0] = v.x; T[row][c4*4+1] = v.y;
        T[row][c4*4+2] = v.z; T[row][c4*4+3] = v.w;
    }
    __syncthreads();
    #pragma unroll
    for (int i = 0; i < 4; i++) {
        int nrow = r + i * 16;
        ushort4 u;
        u.x = f2bf(T[c4*4+0][nrow]); u.y = f2bf(T[c4*4+1][nrow]);
        u.z = f2bf(T[c4*4+2][nrow]); u.w = f2bf(T[c4*4+3][nrow]);
        *(ushort4*)(dst + (size_t)(n0 + nrow) * K + k0 + c4 * 4) = u;
    }
}

// ---------------- bf16 MFMA GEMM: C(M,N) = A(M,K) @ Bt(N,K)^T ----------------
template<int BN, bool OUT_BF16>
__global__ __launch_bounds__(256) void bgemm_kernel(
    const unsigned short* __restrict__ A,    // M x K bf16
    const unsigned short* __restrict__ Bt,   // N x K bf16
    void* __restrict__ Cv,                   // M x N (fp32 or bf16)
    int M, int N, int K)
{
    constexpr int NT = BN / 32;
    constexpr int NSLAB = 8 + BN / 16;
    const int tid  = threadIdx.x;
    const int w    = tid >> 6;
    const int lane = tid & 63;
    const int n16  = lane & 15, quad = lane >> 4;
    const int m0 = blockIdx.y * 128;
    const int n0 = blockIdx.x * BN;
    const int moff = (w & 1) * 64;
    const int noff = (w >> 1) * (NT * 16);

    __shared__ unsigned short As[128 * 32];
    __shared__ unsigned short Bs[BN * 32];

    const unsigned short* gp[4];
    unsigned short* lp[4];
    int ns = 0;
    const int rl = lane >> 2, sc = lane & 3;
    for (int s = w; s < NSLAB; s += 4) {
        int kc = sc ^ (((s * 16 + rl) >> 1) & 3);   // XOR swizzle
        if (s < 8) {
            gp[ns] = A + (size_t)(m0 + s * 16 + rl) * K + kc * 8;
            lp[ns] = As + s * 512;
        } else {
            int sb = s - 8;
            gp[ns] = Bt + (size_t)(n0 + sb * 16 + rl) * K + kc * 8;
            lp[ns] = Bs + sb * 512;
        }
        ns++;
    }

    const int swz = (quad ^ ((n16 >> 1) & 3)) * 8;
    int aoff[4], boff[NT];
    #pragma unroll
    for (int mt = 0; mt < 4; mt++) aoff[mt] = (moff + mt * 16 + n16) * 32 + swz;
    #pragma unroll
    for (int nt = 0; nt < NT; nt++) boff[nt] = (noff + nt * 16 + n16) * 32 + swz;

    f32x4 acc[4][NT];
    #pragma unroll
    for (int mt = 0; mt < 4; mt++)
        #pragma unroll
        for (int nt = 0; nt < NT; nt++) acc[mt][nt] = (f32x4){0.f, 0.f, 0.f, 0.f};

    for (int k0 = 0; k0 < K; k0 += 32) {
        #pragma unroll
        for (int j = 0; j < 4; j++) if (j < ns) gl_lds16(gp[j], lp[j]);
        #pragma unroll
        for (int j = 0; j < 4; j++) if (j < ns) gp[j] += 32;
        __syncthreads();

        short8 af[4], bfr[NT];
        #pragma unroll
        for (int mt = 0; mt < 4; mt++) af[mt] = *(const short8*)(As + aoff[mt]);
        #pragma unroll
        for (int nt = 0; nt < NT; nt++) bfr[nt] = *(const short8*)(Bs + boff[nt]);
        #pragma unroll
        for (int mt = 0; mt < 4; mt++)
            #pragma unroll
            for (int nt = 0; nt < NT; nt++)
                acc[mt][nt] = __builtin_amdgcn_mfma_f32_16x16x32_bf16(
                    af[mt], bfr[nt], acc[mt][nt], 0, 0, 0);
        __syncthreads();
    }

    #pragma unroll
    for (int mt = 0; mt < 4; mt++)
        #pragma unroll
        for (int nt = 0; nt < NT; nt++)
            #pragma unroll
            for (int r = 0; r < 4; r++) {
                size_t idx = (size_t)(m0 + moff + mt * 16 + quad * 4 + r) * N
                           + n0 + noff + nt * 16 + n16;
                if (OUT_BF16) ((unsigned short*)Cv)[idx] = f2bf(acc[mt][nt][r]);
                else          ((float*)Cv)[idx] = acc[mt][nt][r];
            }
}

// ---------------- RMSNorm(kv_c)->bf16 + RoPE(k_rope) ----------------
__global__ __launch_bounds__(256) void kv_norm_rope_kernel(
    const float* __restrict__ kv_full,   // (4096, 576)
    const float* __restrict__ w,         // (512,)
    const float* __restrict__ table,
    unsigned short* __restrict__ kv_cb,  // (4096, 512) bf16
    float* __restrict__ k_rope_out)      // (4096, 64)
{
    const int row = blockIdx.x;
    const int tid = threadIdx.x;
    const float* src = kv_full + (size_t)row * 576;
    float v0 = src[tid], v1 = src[tid + 256];
    float ss = v0*v0 + v1*v1;
    #pragma unroll
    for (int off = 32; off > 0; off >>= 1) ss += __shfl_down(ss, off);
    __shared__ float red[4];
    __shared__ float msh;
    if ((tid & 63) == 0) red[tid >> 6] = ss;
    __syncthreads();
    if (tid == 0) msh = (red[0] + red[1] + red[2] + red[3]) * (1.0f / 512.0f);
    __syncthreads();
    float f = rsqrtf(msh + 1e-6f);
    kv_cb[(size_t)row * 512 + tid]       = f2bf(v0 * f * w[tid]);
    kv_cb[(size_t)row * 512 + tid + 256] = f2bf(v1 * f * w[tid + 256]);
    if (tid < 32) {
        int pos = row & (SEQ - 1);
        float c = table[pos*64 + tid], s = table[pos*64 + 32 + tid];
        float x1 = src[512 + tid], x2 = src[512 + 32 + tid];
        k_rope_out[(size_t)row * 64 + tid]      = x1*c - x2*s;
        k_rope_out[(size_t)row * 64 + 32 + tid] = x2*c + x1*s;
    }
}

// ---------------- RoPE on q (in place, fp32) ----------------
__global__ __launch_bounds__(256) void q_rope_kernel(float* __restrict__ q,
                                                     const float* __restrict__ table) {
    int g = blockIdx.x * 8 + (threadIdx.x >> 5);
    int i = threadIdx.x & 31;
    int row = g >> 4, h = g & 15;
    size_t base = (size_t)row * (NH*HD) + h * HD + D_NOPE;
    int pos = row & (SEQ - 1);
    float c = table[pos*64 + i], s = table[pos*64 + 32 + i];
    float x1 = q[base + i], x2 = q[base + 32 + i];
    q[base + i]      = x1*c - x2*s;
    q[base + 32 + i] = x2*c + x1*s;
}

// ---------------- pack q (roped, fp32) -> Qmat bf16 [b][h][s][192] ----------
__global__ __launch_bounds__(256) void pack_q_kernel(
    const float* __restrict__ q, unsigned short* __restrict__ Qmat)
{
    int wid = blockIdx.x * 4 + (threadIdx.x >> 6);
    int lane = threadIdx.x & 63;
    int row = wid >> 4, h = wid & 15;
    int b = row >> 11, s = row & (SEQ-1);
    const float* src = q + (size_t)row * (NH*HD) + h * HD;
    unsigned short* dst = Qmat + ((size_t)(b*NH + h) * SEQ + s) * HD;
    dst[lane]       = f2bf(src[lane]);
    dst[lane + 64]  = f2bf(src[lane + 64]);
    dst[lane + 128] = f2bf(src[lane + 128]);
}

// ---------------- pack K: kv_exp k_nope + roped k_rope -> Kmat bf16 --------
__global__ __launch_bounds__(256) void pack_k_kernel(
    const float* __restrict__ kv_exp,   // (4096, 4096)
    const float* __restrict__ k_rope,   // (4096, 64) roped
    unsigned short* __restrict__ Kmat)  // [b][h][s][192]
{
    int wid = blockIdx.x * 4 + (threadIdx.x >> 6);
    int lane = threadIdx.x & 63;
    int row = wid >> 4, h = wid & 15;
    int b = row >> 11, s = row & (SEQ-1);
    const float* src = kv_exp + (size_t)row * 4096 + h * 256;
    unsigned short* dst = Kmat + ((size_t)(b*NH + h) * SEQ + s) * HD;
    dst[lane]       = f2bf(src[lane]);
    dst[lane + 64]  = f2bf(src[lane + 64]);
    dst[lane + 128] = f2bf(k_rope[(size_t)row * 64 + lane]);
}

// ---------------- pack V transposed: kv_exp v -> Vmat bf16 [b][h][128][s] --
__global__ __launch_bounds__(256) void pack_vt_kernel(
    const float* __restrict__ kv_exp, unsigned short* __restrict__ Vmat)
{
    const int st = blockIdx.x;
    const int h  = blockIdx.y;
    const int b  = blockIdx.z;
    const int tid = threadIdx.x;
    const int s0 = st * 64;
    __shared__ float T[64][129];

    #pragma unroll
    for (int t = 0; t < 8; t++) {
        int idx = tid + t * 256;
        int tokr = idx >> 5, c4 = idx & 31;
        float4 v = *(const float4*)(kv_exp + ((size_t)(b*SEQ) + s0 + tokr) * 4096 + h*256 + 128 + c4*4);
        T[tokr][c4*4+0] = v.x; T[tokr][c4*4+1] = v.y;
        T[tokr][c4*4+2] = v.z; T[tokr][c4*4+3] = v.w;
    }
    __syncthreads();

    int d = tid >> 1, sh = (tid & 1) * 32;
    unsigned short* op = Vmat + ((size_t)((b*NH + h) * V_DIM + d)) * SEQ + s0 + sh;
    #pragma unroll
    for (int j = 0; j < 32; j += 2) {
        ushort2 u;
        u.x = f2bf(T[sh + j][d]);
        u.y = f2bf(T[sh + j + 1][d]);
        *(ushort2*)(op + j) = u;
    }
}

// ---------------- MFMA flash attention, LDS-staged + double-buffered --------
// grid (S/64, H, B), 256 thr = 4 waves x 16 q-rows. K/V tiles (32 keys) staged
// cooperatively via global_load_lds into double-buffered LDS with XOR swizzle.
__global__ __launch_bounds__(256, 3) void flash_mfma_kernel(
    const unsigned short* __restrict__ Qmat,  // [b][h][s][192]
    const unsigned short* __restrict__ Kmat,  // [b][h][s][192]
    const unsigned short* __restrict__ Vmat,  // [b][h][128][s]
    unsigned short* __restrict__ attnb)       // (4096, 2048) bf16
{
    const int qb  = blockIdx.x;   // 0..31
    const int h   = blockIdx.y;
    const int b   = blockIdx.z;
    const int tid  = threadIdx.x;
    const int w    = tid >> 6;
    const int lane = tid & 63;
    const int n16  = lane & 15;
    const int quad = lane >> 4;

    const int q0 = qb * 64 + w * 16;
    const size_t bh = (size_t)(b * NH + h);
    const unsigned short* qbase = Qmat + bh * SEQ * HD;
    const char* kByte = (const char*)(Kmat + bh * SEQ * HD);
    const char* vByte = (const char*)(Vmat + bh * V_DIM * SEQ);

    // LDS: double-buffered K (6 slabs x 32 keys x 32 elems) and V (128 d x 32 keys)
    __shared__ unsigned short Ks[2][6144];   // 2 x 12 KB
    __shared__ unsigned short Vs[2][4096];   // 2 x 8 KB
    __shared__ unsigned short Plds[4][16][40];

    // staging offsets (bytes), XOR source-swizzle; LDS dest lane-contiguous
    int koff[3], kdst[3], voff[2], vdst[2];
    #pragma unroll
    for (int t = 0; t < 3; t++) {
        int slot = t * 256 + tid;                 // 0..767
        int kc = slot >> 7, key = (slot >> 2) & 31, sc = slot & 3;
        int c = sc ^ ((key >> 1) & 3);
        koff[t] = key * 384 + kc * 64 + c * 16;   // + k0*384
        kdst[t] = slot * 16;
    }
    #pragma unroll
    for (int t = 0; t < 2; t++) {
        int slot = t * 256 + tid;                 // 0..511
        int d = slot >> 2, sc = slot & 3;
        int c = sc ^ ((d >> 1) & 3);
        voff[t] = d * (SEQ * 2) + c * 16;         // + k0*2
        vdst[t] = slot * 16;
    }

    // Q fragments: A[m=n16][k=quad*8+j], 6 chunks of K=32 (from global, once)
    short8 qf[6];
    {
        const unsigned short* qp = qbase + (size_t)(q0 + n16) * HD + quad * 8;
        #pragma unroll
        for (int kc = 0; kc < 6; kc++)
            qf[kc] = *(const short8*)(qp + kc * 32);
    }

    f32x4 O[8];
    #pragma unroll
    for (int c = 0; c < 8; c++) O[c] = (f32x4){0.f, 0.f, 0.f, 0.f};
    float mrow[4] = {-INFINITY, -INFINITY, -INFINITY, -INFINITY};
    float lrow[4] = {0.f, 0.f, 0.f, 0.f};

    const float scale = 0.07216878364870322f;    // 1/sqrt(192)
    const int swz = (quad ^ ((n16 >> 1) & 3)) * 8;
    const int ntB   = qb * 2 + 2;                // block tiles (covers q0_blk+63)
    const int my_nt = (q0 + 47) >> 5;            // wave's compute tiles

    // stage tile 0 into buffer 0
    #pragma unroll
    for (int t = 0; t < 3; t++) gl_lds16(kByte + koff[t], (char*)Ks[0] + kdst[t]);
    #pragma unroll
    for (int t = 0; t < 2; t++) gl_lds16(vByte + voff[t], (char*)Vs[0] + vdst[t]);
    __syncthreads();

    for (int kt = 0; kt < ntB; kt++) {
        const int sel = kt & 1;
        const int k0 = kt * 32;

        // prefetch next tile into the other buffer
        if (kt + 1 < ntB) {
            const int nk0 = k0 + 32;
            #pragma unroll
            for (int t = 0; t < 3; t++)
                gl_lds16(kByte + (size_t)nk0 * 384 + koff[t], (char*)Ks[sel ^ 1] + kdst[t]);
            #pragma unroll
            for (int t = 0; t < 2; t++)
                gl_lds16(vByte + (size_t)nk0 * 2 + voff[t], (char*)Vs[sel ^ 1] + vdst[t]);
        }

        if (kt < my_nt) {
            const unsigned short* ksb = Ks[sel];
            const unsigned short* vsb = Vs[sel];

            // ---- QK^T: two 16-key halves, 6 K-chunks each ----
            f32x4 S[2];
            #pragma unroll
            for (int half = 0; half < 2; half++) {
                f32x4 acc = (f32x4){0.f, 0.f, 0.f, 0.f};
                const int keyoff = (half * 16 + n16) * 32 + swz;
                #pragma unroll
                for (int kc = 0; kc < 6; kc++) {
                    short8 kf = *(const short8*)(ksb + kc * 1024 + keyoff);
                    acc = __builtin_amdgcn_mfma_f32_16x16x32_bf16(qf[kc], kf, acc, 0, 0, 0);
                }
                S[half] = acc;
            }

            // ---- online softmax in C-layout (row=quad*4+r, col=n16) ----
            float p0[4], p1[4], mnew[4];
            #pragma unroll
            for (int r = 0; r < 4; r++) {
                int row = q0 + quad*4 + r;
                float s0v = (k0 + n16      <= row) ? S[0][r] * scale : -INFINITY;
                float s1v = (k0 + 16 + n16 <= row) ? S[1][r] * scale : -INFINITY;
                p0[r] = s0v; p1[r] = s1v;
                float t = fmaxf(s0v, s1v);
                t = fmaxf(t, __shfl_xor(t, 1));
                t = fmaxf(t, __shfl_xor(t, 2));
                t = fmaxf(t, __shfl_xor(t, 4));
                t = fmaxf(t, __shfl_xor(t, 8));
                mnew[r] = fmaxf(mrow[r], t);
            }
            #pragma unroll
            for (int r = 0; r < 4; r++) {
                float alpha = __expf(mrow[r] - mnew[r]);
                float e0 = __expf(p0[r] - mnew[r]);
                float e1 = __expf(p1[r] - mnew[r]);
                float ps = e0 + e1;
                ps += __shfl_xor(ps, 1);
                ps += __shfl_xor(ps, 2);
                ps += __shfl_xor(ps, 4);
                ps += __shfl_xor(ps, 8);
                lrow[r] = lrow[r] * alpha + ps;
                mrow[r] = mnew[r];
                #pragma unroll
                for (int c = 0; c < 8; c++) O[c][r] *= alpha;
                unsigned short* pw = &Plds[w][quad*4 + r][0];
                pw[n16]      = f2bf(e0);
                pw[16 + n16] = f2bf(e1);
            }

            // ---- P as A-frag (per-wave LDS roundtrip), then PV ----
            short8 pf = *(const short8*)(&Plds[w][n16][quad * 8]);
            #pragma unroll
            for (int c = 0; c < 8; c++) {
                short8 vf = *(const short8*)(vsb + (c * 16 + n16) * 32 + swz);
                O[c] = __builtin_amdgcn_mfma_f32_16x16x32_bf16(pf, vf, O[c], 0, 0, 0);
            }
        }
        __syncthreads();
    }

    float invl[4];
    #pragma unroll
    for (int r = 0; r < 4; r++) invl[r] = 1.0f / lrow[r];
    #pragma unroll
    for (int c = 0; c < 8; c++) {
        #pragma unroll
        for (int r = 0; r < 4; r++) {
            size_t tok = (size_t)b * SEQ + q0 + quad*4 + r;
            attnb[tok * (NH*V_DIM) + h * V_DIM + c*16 + n16] = f2bf(O[c][r] * invl[r]);
        }
    }
}

// ---------------- launch ----------------
extern "C" void kernel_launch(void* const* d_in, const int* in_sizes, int n_in,
                              void* d_out, int out_size, void* d_ws, size_t ws_size,
                              hipStream_t stream)
{
    const float* x         = (const float*)d_in[0];
    const float* w_q_down  = (const float*)d_in[1];
    const float* w_q_up    = (const float*)d_in[2];
    const float* w_kv_down = (const float*)d_in[3];
    const float* kv_norm_w = (const float*)d_in[4];
    const float* w_kv_up   = (const float*)d_in[5];
    const float* w_out     = (const float*)d_in[6];
    float* out = (float*)d_out;
    float* ws  = (float*)d_ws;

    // ---- workspace layout (float offsets), lifetime-overlaid ----
    float*          table  = ws;                                      // [0, 131072)
    unsigned short* Qmat   = (unsigned short*)(ws + 131072);
    unsigned short* Kmat   = (unsigned short*)(ws + 6422528);
    unsigned short* Vmat   = (unsigned short*)(ws + 12713984);
    unsigned short* attnb  = (unsigned short*)(ws + 16908288);
    unsigned short* xb     = (unsigned short*)(ws + 19005440);
    float*          q      = ws + 23199744;
    float*          kv_exp = ws + 19005440;                           // overlays xb ∪ q
    unsigned short* wt1    = (unsigned short*)(ws + 35782656);
    unsigned short* wt2    = (unsigned short*)(ws + 37355520);
    unsigned short* wt3    = (unsigned short*)(ws + 39714816);
    unsigned short* wt4    = (unsigned short*)(ws + 40304640);
    unsigned short* wt5    = (unsigned short*)(ws + 41353216);
    unsigned short* qdb    = (unsigned short*)(ws + 43450368);
    float*          kv_full= ws + 43450368;                           // overlays qdb
    unsigned short* kv_cb  = (unsigned short*)(ws + 45809664);
    float*          k_rope = ws + 46858240;                           // end 47120384

    rope_table_kernel<<<512, 256, 0, stream>>>(table);

    convert_bf16_kernel<<<ROWS*HID/1024, 256, 0, stream>>>(x, xb);
    transpose_bf16_kernel<<<dim3(1536/64, 2048/64), 256, 0, stream>>>(w_q_down, wt1, 2048, 1536);
    transpose_bf16_kernel<<<dim3(3072/64, 1536/64), 256, 0, stream>>>(w_q_up,   wt2, 1536, 3072);
    transpose_bf16_kernel<<<dim3(576/64,  2048/64), 256, 0, stream>>>(w_kv_down,wt3, 2048, 576);
    transpose_bf16_kernel<<<dim3(4096/64,  512/64), 256, 0, stream>>>(w_kv_up,  wt4, 512, 4096);
    transpose_bf16_kernel<<<dim3(2048/64, 2048/64), 256, 0, stream>>>(w_out,    wt5, 2048, 2048);

    // q chain
    bgemm_kernel<128, true ><<<dim3(1536/128, ROWS/128), 256, 0, stream>>>(xb,  wt1, qdb, ROWS, 1536, 2048);
    bgemm_kernel<128, false><<<dim3(3072/128, ROWS/128), 256, 0, stream>>>(qdb, wt2, q,   ROWS, 3072, 1536);
    q_rope_kernel<<<8192, 256, 0, stream>>>(q, table);
    pack_q_kernel<<<16384, 256, 0, stream>>>(q, Qmat);

    // kv chain
    bgemm_kernel<64, false><<<dim3(576/64, ROWS/128), 256, 0, stream>>>(xb, wt3, kv_full, ROWS, 576, 2048);
    kv_norm_rope_kernel<<<ROWS, 256, 0, stream>>>(kv_full, kv_norm_w, table, kv_cb, k_rope);
    bgemm_kernel<128, false><<<dim3(4096/128, ROWS/128), 256, 0, stream>>>(kv_cb, wt4, kv_exp, ROWS, 4096, 512);
    pack_k_kernel<<<16384, 256, 0, stream>>>(kv_exp, k_rope, Kmat);
    pack_vt_kernel<<<dim3(SEQ/64, NH, BATCH), 256, 0, stream>>>(kv_exp, Vmat);

    // attention
    flash_mfma_kernel<<<dim3(SEQ/64, NH, BATCH), 256, 0, stream>>>(Qmat, Kmat, Vmat, attnb);

    // output projection
    bgemm_kernel<128, false><<<dim3(2048/128, ROWS/128), 256, 0, stream>>>(attnb, wt5, out, ROWS, 2048, 2048);
}

// Round 6
// 624.500 us; speedup vs baseline: 65.6156x; 1.0125x over previous
//
#include <hip/hip_runtime.h>
#include <hip/hip_bf16.h>
#include <math.h>

// ---------------- problem constants ----------------
#define HID    2048
#define NH     16
#define D_NOPE 128
#define D_ROPE 64
#define HD     192      // HEAD_DIM
#define V_DIM  128
#define KV_RANK 512
#define Q_RANK  1536
#define BATCH  2
#define SEQ    2048
#define ROWS   (BATCH*SEQ)   // 4096

typedef __attribute__((ext_vector_type(8))) short short8;
typedef __attribute__((ext_vector_type(4))) float f32x4;

__device__ __forceinline__ unsigned short f2bf(float x) {
    unsigned int u = __float_as_uint(x);
    unsigned int r = (u + 0x7fffu + ((u >> 16) & 1u)) >> 16;
    return (unsigned short)r;
}
__device__ __forceinline__ float bf2f(unsigned short u) {
    return __uint_as_float((unsigned int)u << 16);
}

typedef const __attribute__((address_space(1))) unsigned int gu32;
typedef __attribute__((address_space(3))) unsigned int lu32;
__device__ __forceinline__ void gl_lds16(const void* g, void* l) {
    __builtin_amdgcn_global_load_lds((gu32*)g, (lu32*)l, 16, 0, 0);
}

// ---------------- RoPE cos/sin table ----------------
__global__ void rope_table_kernel(float* __restrict__ table) {
    int idx = blockIdx.x * 256 + threadIdx.x;   // < 2048*64
    int pos = idx >> 6, u = idx & 63;
    int i = u & 31;
    float invf = expf((float)i * (-9.210340371976184f / 32.0f));
    float ang = (float)pos * invf;
    table[idx] = (u < 32) ? cosf(ang) : sinf(ang);
}

// ---------------- fp32 -> bf16 elementwise ----------------
__global__ __launch_bounds__(256) void convert_bf16_kernel(
    const float* __restrict__ src, unsigned short* __restrict__ dst)
{
    size_t i = (size_t)(blockIdx.x * 256 + threadIdx.x) * 4;
    float4 v = *(const float4*)(src + i);
    ushort4 u;
    u.x = f2bf(v.x); u.y = f2bf(v.y); u.z = f2bf(v.z); u.w = f2bf(v.w);
    *(ushort4*)(dst + i) = u;
}

// ---------------- fp32 (K x N) -> bf16 transposed (N x K) ----------------
__global__ __launch_bounds__(256) void transpose_bf16_kernel(
    const float* __restrict__ src, unsigned short* __restrict__ dst, int K, int N)
{
    __shared__ float T[64][65];
    const int n0 = blockIdx.x * 64, k0 = blockIdx.y * 64;
    const int t = threadIdx.x;
    const int c4 = t & 15, r = t >> 4;
    #pragma unroll
    for (int i = 0; i < 4; i++) {
        int row = r + i * 16;
        float4 v = *(const float4*)(src + (size_t)(k0 + row) * N + n0 + c4 * 4);
        T[row][c4*4+0] = v.x; T[row][c4*4+1] = v.y;
        T[row][c4*4+2] = v.z; T[row][c4*4+3] = v.w;
    }
    __syncthreads();
    #pragma unroll
    for (int i = 0; i < 4; i++) {
        int nrow = r + i * 16;
        ushort4 u;
        u.x = f2bf(T[c4*4+0][nrow]); u.y = f2bf(T[c4*4+1][nrow]);
        u.z = f2bf(T[c4*4+2][nrow]); u.w = f2bf(T[c4*4+3][nrow]);
        *(ushort4*)(dst + (size_t)(n0 + nrow) * K + k0 + c4 * 4) = u;
    }
}

// ---------------- bf16 MFMA GEMM: C(M,N) = A(M,K) @ Bt(N,K)^T ----------------
template<int BN, bool OUT_BF16>
__global__ __launch_bounds__(256) void bgemm_kernel(
    const unsigned short* __restrict__ A,    // M x K bf16
    const unsigned short* __restrict__ Bt,   // N x K bf16
    void* __restrict__ Cv,                   // M x N (fp32 or bf16)
    int M, int N, int K)
{
    constexpr int NT = BN / 32;
    constexpr int NSLAB = 8 + BN / 16;
    const int tid  = threadIdx.x;
    const int w    = tid >> 6;
    const int lane = tid & 63;
    const int n16  = lane & 15, quad = lane >> 4;
    const int m0 = blockIdx.y * 128;
    const int n0 = blockIdx.x * BN;
    const int moff = (w & 1) * 64;
    const int noff = (w >> 1) * (NT * 16);

    __shared__ unsigned short As[128 * 32];
    __shared__ unsigned short Bs[BN * 32];

    const unsigned short* gp[4];
    unsigned short* lp[4];
    int ns = 0;
    const int rl = lane >> 2, sc = lane & 3;
    for (int s = w; s < NSLAB; s += 4) {
        int kc = sc ^ (((s * 16 + rl) >> 1) & 3);   // XOR swizzle
        if (s < 8) {
            gp[ns] = A + (size_t)(m0 + s * 16 + rl) * K + kc * 8;
            lp[ns] = As + s * 512;
        } else {
            int sb = s - 8;
            gp[ns] = Bt + (size_t)(n0 + sb * 16 + rl) * K + kc * 8;
            lp[ns] = Bs + sb * 512;
        }
        ns++;
    }

    const int swz = (quad ^ ((n16 >> 1) & 3)) * 8;
    int aoff[4], boff[NT];
    #pragma unroll
    for (int mt = 0; mt < 4; mt++) aoff[mt] = (moff + mt * 16 + n16) * 32 + swz;
    #pragma unroll
    for (int nt = 0; nt < NT; nt++) boff[nt] = (noff + nt * 16 + n16) * 32 + swz;

    f32x4 acc[4][NT];
    #pragma unroll
    for (int mt = 0; mt < 4; mt++)
        #pragma unroll
        for (int nt = 0; nt < NT; nt++) acc[mt][nt] = (f32x4){0.f, 0.f, 0.f, 0.f};

    for (int k0 = 0; k0 < K; k0 += 32) {
        #pragma unroll
        for (int j = 0; j < 4; j++) if (j < ns) gl_lds16(gp[j], lp[j]);
        #pragma unroll
        for (int j = 0; j < 4; j++) if (j < ns) gp[j] += 32;
        __syncthreads();

        short8 af[4], bfr[NT];
        #pragma unroll
        for (int mt = 0; mt < 4; mt++) af[mt] = *(const short8*)(As + aoff[mt]);
        #pragma unroll
        for (int nt = 0; nt < NT; nt++) bfr[nt] = *(const short8*)(Bs + boff[nt]);
        #pragma unroll
        for (int mt = 0; mt < 4; mt++)
            #pragma unroll
            for (int nt = 0; nt < NT; nt++)
                acc[mt][nt] = __builtin_amdgcn_mfma_f32_16x16x32_bf16(
                    af[mt], bfr[nt], acc[mt][nt], 0, 0, 0);
        __syncthreads();
    }

    #pragma unroll
    for (int mt = 0; mt < 4; mt++)
        #pragma unroll
        for (int nt = 0; nt < NT; nt++)
            #pragma unroll
            for (int r = 0; r < 4; r++) {
                size_t idx = (size_t)(m0 + moff + mt * 16 + quad * 4 + r) * N
                           + n0 + noff + nt * 16 + n16;
                if (OUT_BF16) ((unsigned short*)Cv)[idx] = f2bf(acc[mt][nt][r]);
                else          ((float*)Cv)[idx] = acc[mt][nt][r];
            }
}

// ---------------- RMSNorm(kv_c)->bf16 + RoPE(k_rope)->bf16 ----------------
__global__ __launch_bounds__(256) void kv_norm_rope_kernel(
    const float* __restrict__ kv_full,    // (4096, 576)
    const float* __restrict__ w,          // (512,)
    const float* __restrict__ table,
    unsigned short* __restrict__ kv_cb,   // (4096, 512) bf16
    unsigned short* __restrict__ k_rope_b)// (4096, 64) bf16 roped
{
    const int row = blockIdx.x;
    const int tid = threadIdx.x;
    const float* src = kv_full + (size_t)row * 576;
    float v0 = src[tid], v1 = src[tid + 256];
    float ss = v0*v0 + v1*v1;
    #pragma unroll
    for (int off = 32; off > 0; off >>= 1) ss += __shfl_down(ss, off);
    __shared__ float red[4];
    __shared__ float msh;
    if ((tid & 63) == 0) red[tid >> 6] = ss;
    __syncthreads();
    if (tid == 0) msh = (red[0] + red[1] + red[2] + red[3]) * (1.0f / 512.0f);
    __syncthreads();
    float f = rsqrtf(msh + 1e-6f);
    kv_cb[(size_t)row * 512 + tid]       = f2bf(v0 * f * w[tid]);
    kv_cb[(size_t)row * 512 + tid + 256] = f2bf(v1 * f * w[tid + 256]);
    if (tid < 32) {
        int pos = row & (SEQ - 1);
        float c = table[pos*64 + tid], s = table[pos*64 + 32 + tid];
        float x1 = src[512 + tid], x2 = src[512 + 32 + tid];
        k_rope_b[(size_t)row * 64 + tid]      = f2bf(x1*c - x2*s);
        k_rope_b[(size_t)row * 64 + 32 + tid] = f2bf(x2*c + x1*s);
    }
}

// ---------------- RoPE on q, in place, bf16 ----------------
__global__ __launch_bounds__(256) void q_rope_b_kernel(
    unsigned short* __restrict__ qb16, const float* __restrict__ table)
{
    int g = blockIdx.x * 8 + (threadIdx.x >> 5);  // (row,h) pair id, < 65536
    int i = threadIdx.x & 31;
    int row = g >> 4, h = g & 15;
    size_t base = (size_t)row * (NH*HD) + h * HD + D_NOPE;
    int pos = row & (SEQ - 1);
    float c = table[pos*64 + i], s = table[pos*64 + 32 + i];
    float x1 = bf2f(qb16[base + i]), x2 = bf2f(qb16[base + 32 + i]);
    qb16[base + i]      = f2bf(x1*c - x2*s);
    qb16[base + 32 + i] = f2bf(x2*c + x1*s);
}

// ---------------- pack V transposed: kv_exp_b(v) -> Vmat bf16 [b][h][128][s] --
__global__ __launch_bounds__(256) void pack_vt_kernel(
    const unsigned short* __restrict__ kv_exp_b, unsigned short* __restrict__ Vmat)
{
    const int st = blockIdx.x;     // 32 tiles of 64 tokens
    const int h  = blockIdx.y;
    const int b  = blockIdx.z;
    const int tid = threadIdx.x;
    const int s0 = st * 64;
    __shared__ float T[64][129];

    #pragma unroll
    for (int t = 0; t < 8; t++) {
        int idx = tid + t * 256;            // 0..2047 ushort4 slots
        int tokr = idx >> 5, c4 = idx & 31;
        ushort4 u = *(const ushort4*)(kv_exp_b +
            ((size_t)(b*SEQ) + s0 + tokr) * 4096 + h*256 + 128 + c4*4);
        T[tokr][c4*4+0] = bf2f(u.x); T[tokr][c4*4+1] = bf2f(u.y);
        T[tokr][c4*4+2] = bf2f(u.z); T[tokr][c4*4+3] = bf2f(u.w);
    }
    __syncthreads();

    int d = tid >> 1, sh = (tid & 1) * 32;
    unsigned short* op = Vmat + ((size_t)((b*NH + h) * V_DIM + d)) * SEQ + s0 + sh;
    #pragma unroll
    for (int j = 0; j < 32; j += 2) {
        ushort2 u;
        u.x = f2bf(T[sh + j][d]);
        u.y = f2bf(T[sh + j + 1][d]);
        *(ushort2*)(op + j) = u;
    }
}

// ---------------- MFMA flash attention, fine-grained + single-buffer LDS ----
// grid (S/32, H, B) with qb reversed (LPT), 128 thr = 2 waves x 16 q-rows.
// K staged from kv_exp_b + k_rope_b (two-source global_load_lds), V from Vmat.
__global__ __launch_bounds__(128, 3) void flash_mfma_kernel(
    const unsigned short* __restrict__ qb16,     // (4096, 3072) roped bf16
    const unsigned short* __restrict__ kv_exp_b, // (4096, 4096) bf16
    const unsigned short* __restrict__ k_rope_b, // (4096, 64) bf16 roped
    const unsigned short* __restrict__ Vmat,     // [b][h][128][2048] bf16
    unsigned short* __restrict__ attnb)          // (4096, 2048) bf16
{
    const int qb  = 63 - blockIdx.x;   // longest blocks first
    const int h   = blockIdx.y;
    const int b   = blockIdx.z;
    const int tid  = threadIdx.x;
    const int w    = tid >> 6;
    const int lane = tid & 63;
    const int n16  = lane & 15;
    const int quad = lane >> 4;

    const int q0 = qb * 32 + w * 16;
    const char* kNopeB = (const char*)(kv_exp_b + (size_t)b * SEQ * 4096 + h * 256);
    const char* kRopeB = (const char*)(k_rope_b + (size_t)b * SEQ * 64);
    const char* vByte  = (const char*)(Vmat + (size_t)(b*NH + h) * V_DIM * SEQ);

    __shared__ unsigned short Ks[6144];        // 12 KB: 32 keys x 192
    __shared__ unsigned short Vs[4096];        // 8 KB: 128 d x 32 keys
    __shared__ unsigned short Plds[2][16][40]; // 2.5 KB

    // staging: thread -> key row (tid>>2), 16B sub-chunk (tid&3), XOR swizzle
    const int key = tid >> 2, sc = tid & 3;
    const int cswz = sc ^ ((key >> 1) & 3);

    // Q fragments straight from roped projection output
    short8 qf[6];
    {
        const unsigned short* qp = qb16 + ((size_t)(b*SEQ) + q0 + n16) * (NH*HD)
                                 + h * HD + quad * 8;
        #pragma unroll
        for (int kc = 0; kc < 6; kc++)
            qf[kc] = *(const short8*)(qp + kc * 32);
    }

    f32x4 O[8];
    #pragma unroll
    for (int c = 0; c < 8; c++) O[c] = (f32x4){0.f, 0.f, 0.f, 0.f};
    float mrow[4] = {-INFINITY, -INFINITY, -INFINITY, -INFINITY};
    float lrow[4] = {0.f, 0.f, 0.f, 0.f};

    const float scale = 0.07216878364870322f;    // 1/sqrt(192)
    const int swz = (quad ^ ((n16 >> 1) & 3)) * 8;
    const int ntB = qb + 1;                      // 32-key tiles

    for (int kt = 0; kt < ntB; kt++) {
        const int k0 = kt * 32;

        // ---- stage K (nope from kv_exp_b, rope from k_rope_b) + V ----
        {
            const char* kb0 = kNopeB + (size_t)(k0 + key) * 8192 + cswz * 16;
            #pragma unroll
            for (int t = 0; t < 4; t++)
                gl_lds16(kb0 + t * 64, (char*)Ks + (t*128 + tid) * 16);
            const char* kb1 = kRopeB + (size_t)(k0 + key) * 128 + cswz * 16;
            #pragma unroll
            for (int t = 4; t < 6; t++)
                gl_lds16(kb1 + (t - 4) * 64, (char*)Ks + (t*128 + tid) * 16);
            const char* vb0 = vByte + (size_t)k0 * 2 + cswz * 16;
            #pragma unroll
            for (int t = 0; t < 4; t++)
                gl_lds16(vb0 + (size_t)(t*32 + key) * (SEQ*2), (char*)Vs + (t*128 + tid) * 16);
        }
        __syncthreads();

        // ---- QK^T: two 16-key halves, 6 K-chunks each ----
        f32x4 S[2];
        #pragma unroll
        for (int half = 0; half < 2; half++) {
            f32x4 acc = (f32x4){0.f, 0.f, 0.f, 0.f};
            const int keyoff = (half * 16 + n16) * 32 + swz;
            #pragma unroll
            for (int kc = 0; kc < 6; kc++) {
                short8 kf = *(const short8*)(Ks + kc * 1024 + keyoff);
                acc = __builtin_amdgcn_mfma_f32_16x16x32_bf16(qf[kc], kf, acc, 0, 0, 0);
            }
            S[half] = acc;
        }

        // ---- online softmax in C-layout (row=quad*4+r, col=n16) ----
        float p0[4], p1[4], mnew[4];
        #pragma unroll
        for (int r = 0; r < 4; r++) {
            int row = q0 + quad*4 + r;
            float s0v = (k0 + n16      <= row) ? S[0][r] * scale : -INFINITY;
            float s1v = (k0 + 16 + n16 <= row) ? S[1][r] * scale : -INFINITY;
            p0[r] = s0v; p1[r] = s1v;
            float t = fmaxf(s0v, s1v);
            t = fmaxf(t, __shfl_xor(t, 1));
            t = fmaxf(t, __shfl_xor(t, 2));
            t = fmaxf(t, __shfl_xor(t, 4));
            t = fmaxf(t, __shfl_xor(t, 8));
            mnew[r] = fmaxf(mrow[r], t);
        }
        #pragma unroll
        for (int r = 0; r < 4; r++) {
            float alpha = __expf(mrow[r] - mnew[r]);
            float e0 = __expf(p0[r] - mnew[r]);
            float e1 = __expf(p1[r] - mnew[r]);
            float ps = e0 + e1;
            ps += __shfl_xor(ps, 1);
            ps += __shfl_xor(ps, 2);
            ps += __shfl_xor(ps, 4);
            ps += __shfl_xor(ps, 8);
            lrow[r] = lrow[r] * alpha + ps;
            mrow[r] = mnew[r];
            #pragma unroll
            for (int c = 0; c < 8; c++) O[c][r] *= alpha;
            unsigned short* pw = &Plds[w][quad*4 + r][0];
            pw[n16]      = f2bf(e0);
            pw[16 + n16] = f2bf(e1);
        }

        // ---- P as A-frag (per-wave LDS roundtrip), then PV ----
        short8 pf = *(const short8*)(&Plds[w][n16][quad * 8]);
        #pragma unroll
        for (int c = 0; c < 8; c++) {
            short8 vf = *(const short8*)(Vs + (c * 16 + n16) * 32 + swz);
            O[c] = __builtin_amdgcn_mfma_f32_16x16x32_bf16(pf, vf, O[c], 0, 0, 0);
        }
        __syncthreads();   // protect Ks/Vs before next stage
    }

    float invl[4];
    #pragma unroll
    for (int r = 0; r < 4; r++) invl[r] = 1.0f / lrow[r];
    #pragma unroll
    for (int c = 0; c < 8; c++) {
        #pragma unroll
        for (int r = 0; r < 4; r++) {
            size_t tok = (size_t)b * SEQ + q0 + quad*4 + r;
            attnb[tok * (NH*V_DIM) + h * V_DIM + c*16 + n16] = f2bf(O[c][r] * invl[r]);
        }
    }
}

// ---------------- launch ----------------
extern "C" void kernel_launch(void* const* d_in, const int* in_sizes, int n_in,
                              void* d_out, int out_size, void* d_ws, size_t ws_size,
                              hipStream_t stream)
{
    const float* x         = (const float*)d_in[0];
    const float* w_q_down  = (const float*)d_in[1];
    const float* w_q_up    = (const float*)d_in[2];
    const float* w_kv_down = (const float*)d_in[3];
    const float* kv_norm_w = (const float*)d_in[4];
    const float* w_kv_up   = (const float*)d_in[5];
    const float* w_out     = (const float*)d_in[6];
    float* out = (float*)d_out;
    float* ws  = (float*)d_ws;

    // ---- workspace layout (float offsets), total 41,746,432 floats (~167 MB) ----
    float*          table    = ws;                                // 131072
    unsigned short* xb       = (unsigned short*)(ws + 131072);    // 4096x2048 bf16
    unsigned short* qdb      = (unsigned short*)(ws + 4325376);   // 4096x1536 bf16
    unsigned short* qb16     = (unsigned short*)(ws + 7471104);   // 4096x3072 bf16
    float*          kv_full  = ws + 13762560;                     // 4096x576 fp32
    unsigned short* kv_cb    = (unsigned short*)(ws + 16121856);  // 4096x512 bf16
    unsigned short* k_rope_b = (unsigned short*)(ws + 17170432);  // 4096x64 bf16
    unsigned short* kv_exp_b = (unsigned short*)(ws + 17301504);  // 4096x4096 bf16
    unsigned short* Vmat     = (unsigned short*)(ws + 25690112);  // 2x16x128x2048 bf16
    unsigned short* attnb    = (unsigned short*)(ws + 29884416);  // 4096x2048 bf16
    unsigned short* wt1      = (unsigned short*)(ws + 34078720);  // 1536x2048
    unsigned short* wt2      = (unsigned short*)(ws + 35651584);  // 3072x1536
    unsigned short* wt3      = (unsigned short*)(ws + 38010880);  // 576x2048
    unsigned short* wt4      = (unsigned short*)(ws + 38600704);  // 4096x512
    unsigned short* wt5      = (unsigned short*)(ws + 39649280);  // 2048x2048 -> end 41746432

    rope_table_kernel<<<512, 256, 0, stream>>>(table);

    convert_bf16_kernel<<<ROWS*HID/1024, 256, 0, stream>>>(x, xb);
    transpose_bf16_kernel<<<dim3(1536/64, 2048/64), 256, 0, stream>>>(w_q_down, wt1, 2048, 1536);
    transpose_bf16_kernel<<<dim3(3072/64, 1536/64), 256, 0, stream>>>(w_q_up,   wt2, 1536, 3072);
    transpose_bf16_kernel<<<dim3(576/64,  2048/64), 256, 0, stream>>>(w_kv_down,wt3, 2048, 576);
    transpose_bf16_kernel<<<dim3(4096/64,  512/64), 256, 0, stream>>>(w_kv_up,  wt4, 512, 4096);
    transpose_bf16_kernel<<<dim3(2048/64, 2048/64), 256, 0, stream>>>(w_out,    wt5, 2048, 2048);

    // q chain: x@W1 -> q_down; q_down@W2 -> q (bf16); rope in place
    bgemm_kernel<128, true><<<dim3(1536/128, ROWS/128), 256, 0, stream>>>(xb,  wt1, qdb,  ROWS, 1536, 2048);
    bgemm_kernel<128, true><<<dim3(3072/128, ROWS/128), 256, 0, stream>>>(qdb, wt2, qb16, ROWS, 3072, 1536);
    q_rope_b_kernel<<<8192, 256, 0, stream>>>(qb16, table);

    // kv chain
    bgemm_kernel<64, false><<<dim3(576/64, ROWS/128), 256, 0, stream>>>(xb, wt3, kv_full, ROWS, 576, 2048);
    kv_norm_rope_kernel<<<ROWS, 256, 0, stream>>>(kv_full, kv_norm_w, table, kv_cb, k_rope_b);
    bgemm_kernel<128, true><<<dim3(4096/128, ROWS/128), 256, 0, stream>>>(kv_cb, wt4, kv_exp_b, ROWS, 4096, 512);
    pack_vt_kernel<<<dim3(SEQ/64, NH, BATCH), 256, 0, stream>>>(kv_exp_b, Vmat);

    // attention
    flash_mfma_kernel<<<dim3(SEQ/32, NH, BATCH), 128, 0, stream>>>(qb16, kv_exp_b, k_rope_b, Vmat, attnb);

    // output projection
    bgemm_kernel<128, false><<<dim3(2048/128, ROWS/128), 256, 0, stream>>>(attnb, wt5, out, ROWS, 2048, 2048);
}